// Round 14
// baseline (193.901 us; speedup 1.0000x reference)
//
#include <hip/hip_runtime.h>
#include <hip/hip_bf16.h>
#include <math.h>

// TbpNet: B=16, A=256, NBH=64, F=128, K=25, L=3.
// R13: filter contraction in packed float2 (v_pk_fma_f32); geometry drops one
//      log2 (l1 = -r*log2e exact where fc != 0). Structure unchanged from R12.
#define NB   16
#define NA   256
#define NNBH 64
#define NF   128
#define NK   25
#define NATOM (NB*NA)   // 4096

typedef __attribute__((ext_vector_type(2))) float f32x2;
typedef __attribute__((ext_vector_type(4))) float f32x4;
typedef __attribute__((ext_vector_type(8))) short bf16x8;

__device__ __constant__ float BINOM_C[25] = {
  1.f, 24.f, 276.f, 2024.f, 10626.f, 42504.f, 134596.f, 346104.f,
  735471.f, 1307504.f, 1961256.f, 2496144.f, 2704156.f, 2496144.f,
  1961256.f, 1307504.f, 735471.f, 346104.f, 134596.f, 42504.f,
  10626.f, 2024.f, 276.f, 24.f, 1.f
};

__device__ __forceinline__ float sspf(float x) {
  float t = (x > 20.f) ? x : log1pf(expf(x));
  return t - 0.69314718055994531f;
}
__device__ __forceinline__ unsigned short f2bf(float x) {
  __hip_bfloat16 h = __float2bfloat16(x);
  return *(unsigned short*)&h;
}

// ---------------- init: WT prep + Wfb prep ----------------
__global__ __launch_bounds__(256) void k_init(
    const float* __restrict__ Win, const float* __restrict__ Wf2o,
    const float* __restrict__ Wd, const float* __restrict__ Wq,
    const float* __restrict__ Wk, const float* __restrict__ Wv,
    const float* __restrict__ Wfs, const float* __restrict__ Wfp,
    __hip_bfloat16* __restrict__ WT, __hip_bfloat16* __restrict__ Wfb) {
  int bid = blockIdx.x, tid = threadIdx.x;
  if (bid < 1152) {
    int idx = bid * 256 + tid;               // 18*16384
    int e = idx & 16383; int m = idx >> 14;
    int l = m / 6, wsel = m - l * 6;
    const float* src = (wsel == 0) ? Win : (wsel == 1) ? Wf2o : (wsel == 2) ? Wd
                      : (wsel == 3) ? Wq : (wsel == 4) ? Wk : Wv;
    int k = e >> 7, col = e & 127;
    WT[m * 16384 + col * 128 + k] = __float2bfloat16(src[l * NF * NF + k * NF + col]);
  } else {
    int idx = (bid - 1152) * 256 + tid;      // 24576
    int k = idx & 31, f = (idx >> 5) & 127, s = (idx >> 12) & 1, l = idx >> 13;
    float v = 0.f;
    if (k < NK) v = (s ? Wfp : Wfs)[l * NK * NF + k * NF + f];
    Wfb[idx] = __float2bfloat16(v);          // [l][s][f][k]
  }
}

// ---------------- proj: 512 thr. [phase A: hv(prev)+residual] + QKVY ----------
template<int HV>
__global__ __launch_bounds__(512) void k_proj(
    const float* __restrict__ xg, const int* __restrict__ Z,
    const float* __restrict__ emb,
    const float* __restrict__ Cb, const float* __restrict__ Nb,
    const __hip_bfloat16* __restrict__ WTf2o_p, const float* __restrict__ bf2o_p,
    const __hip_bfloat16* __restrict__ WTd_p, const float* __restrict__ bd_p,
    const float* __restrict__ amask, const __hip_bfloat16* __restrict__ WTl,
    float* __restrict__ xout,
    __hip_bfloat16* __restrict__ ybf, __hip_bfloat16* __restrict__ Qw,
    __hip_bfloat16* __restrict__ Kw, __hip_bfloat16* __restrict__ VwT) {
  __shared__ __hip_bfloat16 hLDS[16 * 132];
  __shared__ float xLDS[16 * 133];
  int tid = threadIdx.x;
  int w = tid >> 6, ln = tid & 63, lr = ln & 15, lg = ln >> 4;
  int rbase = blockIdx.x * 16;

  if (HV) {
    bf16x8 cfr[4];
    const float* cr = Cb + (rbase + lr) * NF;
    #pragma unroll
    for (int ks = 0; ks < 4; ks++) {
      int k0 = ks * 32 + lg * 8;
      float4 a = *(const float4*)&cr[k0];
      float4 c = *(const float4*)&cr[k0 + 4];
      bf16x8 t;
      t[0] = (short)f2bf(a.x); t[1] = (short)f2bf(a.y);
      t[2] = (short)f2bf(a.z); t[3] = (short)f2bf(a.w);
      t[4] = (short)f2bf(c.x); t[5] = (short)f2bf(c.y);
      t[6] = (short)f2bf(c.z); t[7] = (short)f2bf(c.w);
      cfr[ks] = t;
    }
    int col = w * 16 + lr;
    f32x4 hacc = (f32x4){0.f, 0.f, 0.f, 0.f};
    #pragma unroll
    for (int ks = 0; ks < 4; ks++) {
      bf16x8 bfr = *(const bf16x8*)(WTf2o_p + col * NF + ks * 32 + lg * 8);
      hacc = __builtin_amdgcn_mfma_f32_16x16x32_bf16(cfr[ks], bfr, hacc, 0, 0, 0);
    }
    float bv = bf2o_p[col];
    #pragma unroll
    for (int r = 0; r < 4; r++)
      hLDS[(4 * lg + r) * 132 + col] = __float2bfloat16(sspf(hacc[r] + bv));
    __syncthreads();
    bf16x8 hfr[4];
    #pragma unroll
    for (int ks = 0; ks < 4; ks++)
      hfr[ks] = *(const bf16x8*)&hLDS[lr * 132 + ks * 32 + lg * 8];
    f32x4 vacc = (f32x4){0.f, 0.f, 0.f, 0.f};
    #pragma unroll
    for (int ks = 0; ks < 4; ks++) {
      bf16x8 bfr = *(const bf16x8*)(WTd_p + col * NF + ks * 32 + lg * 8);
      vacc = __builtin_amdgcn_mfma_f32_16x16x32_bf16(hfr[ks], bfr, vacc, 0, 0, 0);
    }
    float bdv = bd_p[col];
    #pragma unroll
    for (int r = 0; r < 4; r++) {
      int row = rbase + 4 * lg + r;
      float xv = xg[row * NF + col] + vacc[r] + bdv + Nb[row * NF + col];
      xout[row * NF + col] = xv;
      xLDS[(4 * lg + r) * 133 + col] = xv;
    }
    __syncthreads();
  } else {
    int rr = tid >> 5, c0 = (tid & 31) * 4;
    int row = rbase + rr;
    float4 a = *(const float4*)&emb[Z[row] * NF + c0];
    *(float4*)&xout[row * NF + c0] = a;
    xLDS[rr * 133 + c0 + 0] = a.x; xLDS[rr * 133 + c0 + 1] = a.y;
    xLDS[rr * 133 + c0 + 2] = a.z; xLDS[rr * 133 + c0 + 3] = a.w;
    __syncthreads();
  }

  // phase B: 8 waves = 4 projections x 2 col-halves
  int z = w & 3, half = w >> 2;
  const __hip_bfloat16* WT = WTl + ((z == 0) ? 0 : (z + 2)) * (NF * NF);
  float am = (z > 0) ? amask[rbase + lr] : 1.0f;
  bf16x8 afr[4];
  #pragma unroll
  for (int ks = 0; ks < 4; ks++) {
    int k0 = ks * 32 + lg * 8;
    bf16x8 t;
    #pragma unroll
    for (int jj = 0; jj < 8; jj++)
      t[jj] = (short)f2bf(xLDS[lr * 133 + k0 + jj] * am);
    afr[ks] = t;
  }

  f32x4 acc[4];
  #pragma unroll
  for (int t = 0; t < 4; t++) acc[t] = (f32x4){0.f, 0.f, 0.f, 0.f};
  #pragma unroll
  for (int ks = 0; ks < 4; ks++)
    #pragma unroll
    for (int t = 0; t < 4; t++) {
      int nt = half * 4 + t;
      bf16x8 bfr = *(const bf16x8*)(WT + (nt * 16 + lr) * NF + ks * 32 + lg * 8);
      acc[t] = __builtin_amdgcn_mfma_f32_16x16x32_bf16(afr[ks], bfr, acc[t], 0, 0, 0);
    }

  if (z < 3) {
    __hip_bfloat16* out = (z == 0) ? ybf : (z == 1) ? Qw : Kw;
    #pragma unroll
    for (int t = 0; t < 4; t++) {
      int col = (half * 4 + t) * 16 + lr;
      #pragma unroll
      for (int r = 0; r < 4; r++) {
        int orow = rbase + lg * 4 + r;
        float o = acc[t][r];
        if (z > 0) o = sspf(o);
        out[orow * NF + col] = __float2bfloat16(o);
      }
    }
  } else {
    int b = blockIdx.x >> 4;
    int ar0 = (blockIdx.x & 15) * 16 + lg * 4;
    #pragma unroll
    for (int t = 0; t < 4; t++) {
      int col = (half * 4 + t) * 16 + lr;
      #pragma unroll
      for (int r = 0; r < 4; r++)
        VwT[(b * NF + col) * NA + ar0 + r] = __float2bfloat16(sspf(acc[t][r]));
    }
  }
}

// ---------------- fa: blocks<4096 filter, else attn-core -> Nb ----------------
__global__ __launch_bounds__(256) void k_fa(
    const __hip_bfloat16* __restrict__ ybf, const int* __restrict__ nbrs,
    const float* __restrict__ pos, const float* __restrict__ nmask,
    const __hip_bfloat16* __restrict__ Wfb_l, float* __restrict__ cOut,
    const __hip_bfloat16* __restrict__ Qw, const __hip_bfloat16* __restrict__ Kw,
    const __hip_bfloat16* __restrict__ VwT, const float* __restrict__ amask,
    float* __restrict__ Nb) {
  __shared__ char smem[8832];
  int tid = threadIdx.x;
  int lane = tid & 63, w = tid >> 6, lr = lane & 15, lg = lane >> 4;

  if (blockIdx.x < 4096) {
    // ================= filter =================
    __hip_bfloat16* FF  = (__hip_bfloat16*)smem;            // [64][40]  5120 B
    float (*d3l)[4]     = (float(*)[4])(smem + 5120);       // [64][4]   1024 B
    int* jl             = (int*)(smem + 6144);              // [64]       256 B
    int atom = blockIdx.x, brow = atom & ~(NA - 1);
    const unsigned short* yu = (const unsigned short*)ybf;

    {
      int n = tid & 63;
      int j = nbrs[atom * NNBH + n];
      float px = pos[(brow + j) * 3 + 0] - pos[atom * 3 + 0];
      float py = pos[(brow + j) * 3 + 1] - pos[atom * 3 + 1];
      float pz = pos[(brow + j) * 3 + 2] - pos[atom * 3 + 2];
      float m = nmask[atom * NNBH + n];
      float r = sqrtf(px * px + py * py + pz * pz + 1e-12f) * m;
      float inv = 1.0f / (r + 1e-9f);
      float fc = (r < 5.0f) ? (0.5f * cosf(0.62831853071795865f * r) + 0.5f) * m : 0.0f;
      float xe = expf(-r);
      // l1 = log2(xe + 1e-10) == -r*log2(e) wherever fc != 0 (r<=5 -> xe>=6.7e-3)
      float l1 = -1.44269504088896f * r;
      float l2 = log2f(1.0f - xe + 1e-10f);
      if (tid < NNBH) {
        jl[n] = (brow + j) * NF;
        d3l[n][0] = 0.f;
        d3l[n][1] = px * inv;
        d3l[n][2] = py * inv;
        d3l[n][3] = pz * inv;
      }
      int kq = tid >> 6;
      bf16x8 v;
      #pragma unroll
      for (int j8 = 0; j8 < 8; j8++) {
        int k = kq * 8 + j8;
        float val = 0.f;
        if (k < NK)
          val = BINOM_C[k] * exp2f((float)k * l1 + (float)(24 - k) * l2) * fc;
        v[j8] = (short)f2bf(val);
      }
      *(bf16x8*)&FF[n * 40 + kq * 8] = v;
    }
    __syncthreads();

    bf16x8 af[4];
    #pragma unroll
    for (int mt = 0; mt < 4; mt++)
      af[mt] = *(bf16x8*)&FF[(16 * mt + lr) * 40 + lg * 8];

    f32x4 as_[4][2], ap_[4][2];
    #pragma unroll
    for (int mt = 0; mt < 4; mt++)
      #pragma unroll
      for (int nt2 = 0; nt2 < 2; nt2++) {
        as_[mt][nt2] = (f32x4){0.f, 0.f, 0.f, 0.f};
        ap_[mt][nt2] = (f32x4){0.f, 0.f, 0.f, 0.f};
      }
    #pragma unroll
    for (int nt2 = 0; nt2 < 2; nt2++) {
      int col = 32 * w + 16 * nt2 + lr;
      bf16x8 bs = *(const bf16x8*)&Wfb_l[col * 32 + lg * 8];
      bf16x8 bp = *(const bf16x8*)&Wfb_l[(128 + col) * 32 + lg * 8];
      #pragma unroll
      for (int mt = 0; mt < 4; mt++) {
        as_[mt][nt2] = __builtin_amdgcn_mfma_f32_16x16x32_bf16(af[mt], bs, as_[mt][nt2], 0, 0, 0);
        ap_[mt][nt2] = __builtin_amdgcn_mfma_f32_16x16x32_bf16(af[mt], bp, ap_[mt][nt2], 0, 0, 0);
      }
    }

    // contraction: yj direct from global (coalesced u16), packed f32x2 math
    int rb[4][4];
    #pragma unroll
    for (int mt = 0; mt < 4; mt++)
      #pragma unroll
      for (int r = 0; r < 4; r++)
        rb[mt][r] = jl[16 * mt + 4 * lg + r];
    int f0 = 32 * w + lr, f1 = f0 + 16;

    f32x2 qs = {0.f, 0.f}, q1 = {0.f, 0.f}, q2 = {0.f, 0.f}, q3 = {0.f, 0.f};
    #pragma unroll
    for (int mt = 0; mt < 4; mt++) {
      #pragma unroll
      for (int r = 0; r < 4; r++) {
        int n = 16 * mt + 4 * lg + r;
        float4 dv = *(const float4*)&d3l[n][0];
        int rbm = rb[mt][r];
        unsigned short u0 = yu[rbm + f0];
        unsigned short u1 = yu[rbm + f1];
        f32x2 yv = { __bfloat162float(*(__hip_bfloat16*)&u0),
                     __bfloat162float(*(__hip_bfloat16*)&u1) };
        f32x2 as2 = { as_[mt][0][r], as_[mt][1][r] };
        f32x2 ap2 = { ap_[mt][0][r], ap_[mt][1][r] };
        qs += yv * as2;
        f32x2 pw = yv * ap2;
        q1 += dv.y * pw;
        q2 += dv.z * pw;
        q3 += dv.w * pw;
      }
    }
    #pragma unroll
    for (int nt2 = 0; nt2 < 2; nt2++) {
      float a = qs[nt2], b1 = q1[nt2], b2 = q2[nt2], b3 = q3[nt2];
      a  += __shfl_xor(a, 16);  a  += __shfl_xor(a, 32);
      b1 += __shfl_xor(b1, 16); b1 += __shfl_xor(b1, 32);
      b2 += __shfl_xor(b2, 16); b2 += __shfl_xor(b2, 32);
      b3 += __shfl_xor(b3, 16); b3 += __shfl_xor(b3, 32);
      if (lg == 0)
        cOut[atom * NF + 32 * w + 16 * nt2 + lr] = a + b1 * b1 + b2 * b2 + b3 * b3;
    }
  } else {
    // ================= attn-core -> Nb =================
    __hip_bfloat16* Plds = (__hip_bfloat16*)smem;           // [16][260] 8320 B
    float* mwl = (float*)(smem + 8320);                     // [4][16]
    float* swl = (float*)(smem + 8576);                     // [4][16]
    int bb = blockIdx.x - 4096;
    int b = bb >> 4, qt = bb & 15;
    int qbase = b * NA + qt * 16;
    const float scale = 0.08838834764831845f;

    bf16x8 qf[4];
    #pragma unroll
    for (int ks = 0; ks < 4; ks++)
      qf[ks] = *(const bf16x8*)&Qw[(qbase + lr) * NF + ks * 32 + lg * 8];

    f32x4 sacc[4];
    #pragma unroll
    for (int ntc = 0; ntc < 4; ntc++) sacc[ntc] = (f32x4){0.f, 0.f, 0.f, 0.f};
    #pragma unroll
    for (int ks = 0; ks < 4; ks++)
      #pragma unroll
      for (int ntc = 0; ntc < 4; ntc++) {
        bf16x8 kf = *(const bf16x8*)&Kw[(b * NA + w * 64 + ntc * 16 + lr) * NF + ks * 32 + lg * 8];
        sacc[ntc] = __builtin_amdgcn_mfma_f32_16x16x32_bf16(qf[ks], kf, sacc[ntc], 0, 0, 0);
      }

    float kam[4];
    #pragma unroll
    for (int ntc = 0; ntc < 4; ntc++)
      kam[ntc] = (1.0f - amask[b * NA + w * 64 + ntc * 16 + lr]) * (-1e9f);

    #pragma unroll
    for (int r = 0; r < 4; r++) {
      float lv[4], cm = -1e30f;
      #pragma unroll
      for (int ntc = 0; ntc < 4; ntc++) {
        lv[ntc] = sacc[ntc][r] * scale + kam[ntc];
        cm = fmaxf(cm, lv[ntc]);
      }
      cm = fmaxf(cm, __shfl_xor(cm, 1)); cm = fmaxf(cm, __shfl_xor(cm, 2));
      cm = fmaxf(cm, __shfl_xor(cm, 4)); cm = fmaxf(cm, __shfl_xor(cm, 8));
      float ps = 0.f;
      #pragma unroll
      for (int ntc = 0; ntc < 4; ntc++) {
        float pp = expf(lv[ntc] - cm);
        Plds[(4 * lg + r) * 260 + w * 64 + ntc * 16 + lr] = __float2bfloat16(pp);
        ps += pp;
      }
      ps += __shfl_xor(ps, 1); ps += __shfl_xor(ps, 2);
      ps += __shfl_xor(ps, 4); ps += __shfl_xor(ps, 8);
      if (lr == 0) {
        mwl[w * 16 + 4 * lg + r] = cm;
        swl[w * 16 + 4 * lg + r] = ps;
      }
    }
    __syncthreads();

    float ec[4][4], inv_[4];
    #pragma unroll
    for (int r = 0; r < 4; r++) {
      int row = 4 * lg + r;
      float m0 = mwl[row], m1 = mwl[16 + row], m2 = mwl[32 + row], m3 = mwl[48 + row];
      float M = fmaxf(fmaxf(m0, m1), fmaxf(m2, m3));
      float e0 = expf(m0 - M), e1 = expf(m1 - M), e2 = expf(m2 - M), e3 = expf(m3 - M);
      ec[0][r] = e0; ec[1][r] = e1; ec[2][r] = e2; ec[3][r] = e3;
      float s = swl[row] * e0 + swl[16 + row] * e1 + swl[32 + row] * e2 + swl[48 + row] * e3;
      inv_[r] = amask[qbase + row] / s;
    }

    f32x4 O[2];
    O[0] = (f32x4){0.f, 0.f, 0.f, 0.f};
    O[1] = (f32x4){0.f, 0.f, 0.f, 0.f};
    #pragma unroll
    for (int c = 0; c < 4; c++) {
      bf16x8 pf[2];
      #pragma unroll
      for (int s2 = 0; s2 < 2; s2++)
        pf[s2] = *(const bf16x8*)&Plds[lr * 260 + c * 64 + s2 * 32 + lg * 8];
      f32x4 tc[2];
      tc[0] = (f32x4){0.f, 0.f, 0.f, 0.f};
      tc[1] = (f32x4){0.f, 0.f, 0.f, 0.f};
      #pragma unroll
      for (int s2 = 0; s2 < 2; s2++)
        #pragma unroll
        for (int j = 0; j < 2; j++) {
          bf16x8 vf = *(const bf16x8*)&VwT[(b * NF + (2 * w + j) * 16 + lr) * NA + c * 64 + s2 * 32 + lg * 8];
          tc[j] = __builtin_amdgcn_mfma_f32_16x16x32_bf16(pf[s2], vf, tc[j], 0, 0, 0);
        }
      #pragma unroll
      for (int j = 0; j < 2; j++)
        #pragma unroll
        for (int r = 0; r < 4; r++)
          O[j][r] += ec[c][r] * tc[j][r];
    }

    #pragma unroll
    for (int r = 0; r < 4; r++) {
      int q = qbase + 4 * lg + r;
      #pragma unroll
      for (int j = 0; j < 2; j++) {
        int col = (2 * w + j) * 16 + lr;
        Nb[q * NF + col] = O[j][r] * inv_[r];
      }
    }
  }
}

// ---------------- final: hv(L2) + residual -> x (512 thr) ----------------
__global__ __launch_bounds__(512) void k_final(
    const float* __restrict__ Cb, const float* __restrict__ Nb,
    const __hip_bfloat16* __restrict__ WTf2o_p, const float* __restrict__ bf2o_p,
    const __hip_bfloat16* __restrict__ WTd_p, const float* __restrict__ bd_p,
    float* __restrict__ x) {
  __shared__ __hip_bfloat16 hLDS[16 * 132];
  int tid = threadIdx.x;
  int w = tid >> 6, ln = tid & 63, lr = ln & 15, lg = ln >> 4;
  int rbase = blockIdx.x * 16;
  int col = w * 16 + lr;

  bf16x8 cfr[4];
  const float* cr = Cb + (rbase + lr) * NF;
  #pragma unroll
  for (int ks = 0; ks < 4; ks++) {
    int k0 = ks * 32 + lg * 8;
    float4 a = *(const float4*)&cr[k0];
    float4 c = *(const float4*)&cr[k0 + 4];
    bf16x8 t;
    t[0] = (short)f2bf(a.x); t[1] = (short)f2bf(a.y);
    t[2] = (short)f2bf(a.z); t[3] = (short)f2bf(a.w);
    t[4] = (short)f2bf(c.x); t[5] = (short)f2bf(c.y);
    t[6] = (short)f2bf(c.z); t[7] = (short)f2bf(c.w);
    cfr[ks] = t;
  }
  f32x4 hacc = (f32x4){0.f, 0.f, 0.f, 0.f};
  #pragma unroll
  for (int ks = 0; ks < 4; ks++) {
    bf16x8 bfr = *(const bf16x8*)(WTf2o_p + col * NF + ks * 32 + lg * 8);
    hacc = __builtin_amdgcn_mfma_f32_16x16x32_bf16(cfr[ks], bfr, hacc, 0, 0, 0);
  }
  float bv = bf2o_p[col];
  #pragma unroll
  for (int r = 0; r < 4; r++)
    hLDS[(4 * lg + r) * 132 + col] = __float2bfloat16(sspf(hacc[r] + bv));
  __syncthreads();
  bf16x8 hfr[4];
  #pragma unroll
  for (int ks = 0; ks < 4; ks++)
    hfr[ks] = *(const bf16x8*)&hLDS[lr * 132 + ks * 32 + lg * 8];
  f32x4 vacc = (f32x4){0.f, 0.f, 0.f, 0.f};
  #pragma unroll
  for (int ks = 0; ks < 4; ks++) {
    bf16x8 bfr = *(const bf16x8*)(WTd_p + col * NF + ks * 32 + lg * 8);
    vacc = __builtin_amdgcn_mfma_f32_16x16x32_bf16(hfr[ks], bfr, vacc, 0, 0, 0);
  }
  float bdv = bd_p[col];
  #pragma unroll
  for (int r = 0; r < 4; r++) {
    int row = rbase + 4 * lg + r;
    x[row * NF + col] += vacc[r] + bdv + Nb[row * NF + col];
  }
}

// ---------------- host launch ----------------
extern "C" void kernel_launch(void* const* d_in, const int* in_sizes, int n_in,
                              void* d_out, int out_size, void* d_ws, size_t ws_size,
                              hipStream_t stream) {
  const float* pos   = (const float*)d_in[0];
  const float* nmask = (const float*)d_in[1];
  const float* amask = (const float*)d_in[2];
  const float* emb   = (const float*)d_in[3];
  const float* Wfs   = (const float*)d_in[4];
  const float* Wfp   = (const float*)d_in[5];
  const float* Win   = (const float*)d_in[6];
  const float* Wf2o  = (const float*)d_in[7];
  const float* bf2o  = (const float*)d_in[8];
  const float* Wd    = (const float*)d_in[9];
  const float* bd    = (const float*)d_in[10];
  const float* Wq    = (const float*)d_in[11];
  const float* Wk    = (const float*)d_in[12];
  const float* Wv    = (const float*)d_in[13];
  const int*   Z     = (const int*)d_in[14];
  const int*   nbrs  = (const int*)d_in[15];

  float* x = (float*)d_out;
  float* wsf = (float*)d_ws;
  const int S = NATOM * NF;                               // 524288
  float* Cb = wsf;                                        // S f32
  float* Nb = wsf + S;                                    // S f32
  __hip_bfloat16* ybf = (__hip_bfloat16*)(wsf + 2 * S);
  __hip_bfloat16* Qw  = ybf + S;
  __hip_bfloat16* Kw  = Qw + S;
  __hip_bfloat16* VwT = Kw + S;                           // [b][f][row]
  __hip_bfloat16* WT  = VwT + S;                          // 18*16384 bf16
  __hip_bfloat16* Wfb = WT + 18 * 16384;                  // 24576 bf16

  k_init<<<dim3(1248), dim3(256), 0, stream>>>(
      Win, Wf2o, Wd, Wq, Wk, Wv, Wfs, Wfp, WT, Wfb);

  for (int l = 0; l < 3; l++) {
    const __hip_bfloat16* WTl = WT + l * 6 * 16384;
    if (l == 0)
      k_proj<0><<<dim3(256), dim3(512), 0, stream>>>(
          nullptr, Z, emb, nullptr, nullptr, nullptr, nullptr, nullptr, nullptr,
          amask, WTl, x, ybf, Qw, Kw, VwT);
    else {
      const __hip_bfloat16* WTp = WT + (l - 1) * 6 * 16384;
      k_proj<1><<<dim3(256), dim3(512), 0, stream>>>(
          x, nullptr, nullptr, Cb, Nb, WTp + 16384, bf2o + (l - 1) * NF,
          WTp + 2 * 16384, bd + (l - 1) * NF, amask, WTl, x, ybf, Qw, Kw, VwT);
    }
    k_fa<<<dim3(4096 + 256), dim3(256), 0, stream>>>(
        ybf, nbrs, pos, nmask, Wfb + l * 8192, Cb, Qw, Kw, VwT, amask, Nb);
  }
  const __hip_bfloat16* WT2 = WT + 2 * 6 * 16384;
  k_final<<<dim3(256), dim3(512), 0, stream>>>(
      Cb, Nb, WT2 + 16384, bf2o + 2 * NF, WT2 + 2 * 16384, bd + 2 * NF, x);
}

// Round 15
// 191.127 us; speedup vs baseline: 1.0145x; 1.0145x over previous
//
#include <hip/hip_runtime.h>
#include <hip/hip_bf16.h>
#include <math.h>

// TbpNet: B=16, A=256, NBH=64, F=128, K=25, L=3.
// R14: revert R13 (packed-f32x2 shrank the in-flight load window; fa 35->45us).
//      R12 base + explicit 32-load register preload in filter contraction.
#define NB   16
#define NA   256
#define NNBH 64
#define NF   128
#define NK   25
#define NATOM (NB*NA)   // 4096

typedef __attribute__((ext_vector_type(4))) float f32x4;
typedef __attribute__((ext_vector_type(8))) short bf16x8;

__device__ __constant__ float BINOM_C[25] = {
  1.f, 24.f, 276.f, 2024.f, 10626.f, 42504.f, 134596.f, 346104.f,
  735471.f, 1307504.f, 1961256.f, 2496144.f, 2704156.f, 2496144.f,
  1961256.f, 1307504.f, 735471.f, 346104.f, 134596.f, 42504.f,
  10626.f, 2024.f, 276.f, 24.f, 1.f
};

__device__ __forceinline__ float sspf(float x) {
  float t = (x > 20.f) ? x : log1pf(expf(x));
  return t - 0.69314718055994531f;
}
__device__ __forceinline__ unsigned short f2bf(float x) {
  __hip_bfloat16 h = __float2bfloat16(x);
  return *(unsigned short*)&h;
}

// ---------------- init: WT prep + Wfb prep ----------------
__global__ __launch_bounds__(256) void k_init(
    const float* __restrict__ Win, const float* __restrict__ Wf2o,
    const float* __restrict__ Wd, const float* __restrict__ Wq,
    const float* __restrict__ Wk, const float* __restrict__ Wv,
    const float* __restrict__ Wfs, const float* __restrict__ Wfp,
    __hip_bfloat16* __restrict__ WT, __hip_bfloat16* __restrict__ Wfb) {
  int bid = blockIdx.x, tid = threadIdx.x;
  if (bid < 1152) {
    int idx = bid * 256 + tid;               // 18*16384
    int e = idx & 16383; int m = idx >> 14;
    int l = m / 6, wsel = m - l * 6;
    const float* src = (wsel == 0) ? Win : (wsel == 1) ? Wf2o : (wsel == 2) ? Wd
                      : (wsel == 3) ? Wq : (wsel == 4) ? Wk : Wv;
    int k = e >> 7, col = e & 127;
    WT[m * 16384 + col * 128 + k] = __float2bfloat16(src[l * NF * NF + k * NF + col]);
  } else {
    int idx = (bid - 1152) * 256 + tid;      // 24576
    int k = idx & 31, f = (idx >> 5) & 127, s = (idx >> 12) & 1, l = idx >> 13;
    float v = 0.f;
    if (k < NK) v = (s ? Wfp : Wfs)[l * NK * NF + k * NF + f];
    Wfb[idx] = __float2bfloat16(v);          // [l][s][f][k]
  }
}

// ---------------- proj: 512 thr. [phase A: hv(prev)+residual] + QKVY ----------
template<int HV>
__global__ __launch_bounds__(512) void k_proj(
    const float* __restrict__ xg, const int* __restrict__ Z,
    const float* __restrict__ emb,
    const float* __restrict__ Cb, const float* __restrict__ Nb,
    const __hip_bfloat16* __restrict__ WTf2o_p, const float* __restrict__ bf2o_p,
    const __hip_bfloat16* __restrict__ WTd_p, const float* __restrict__ bd_p,
    const float* __restrict__ amask, const __hip_bfloat16* __restrict__ WTl,
    float* __restrict__ xout,
    __hip_bfloat16* __restrict__ ybf, __hip_bfloat16* __restrict__ Qw,
    __hip_bfloat16* __restrict__ Kw, __hip_bfloat16* __restrict__ VwT) {
  __shared__ __hip_bfloat16 hLDS[16 * 132];
  __shared__ float xLDS[16 * 133];
  int tid = threadIdx.x;
  int w = tid >> 6, ln = tid & 63, lr = ln & 15, lg = ln >> 4;
  int rbase = blockIdx.x * 16;

  if (HV) {
    bf16x8 cfr[4];
    const float* cr = Cb + (rbase + lr) * NF;
    #pragma unroll
    for (int ks = 0; ks < 4; ks++) {
      int k0 = ks * 32 + lg * 8;
      float4 a = *(const float4*)&cr[k0];
      float4 c = *(const float4*)&cr[k0 + 4];
      bf16x8 t;
      t[0] = (short)f2bf(a.x); t[1] = (short)f2bf(a.y);
      t[2] = (short)f2bf(a.z); t[3] = (short)f2bf(a.w);
      t[4] = (short)f2bf(c.x); t[5] = (short)f2bf(c.y);
      t[6] = (short)f2bf(c.z); t[7] = (short)f2bf(c.w);
      cfr[ks] = t;
    }
    int col = w * 16 + lr;
    f32x4 hacc = (f32x4){0.f, 0.f, 0.f, 0.f};
    #pragma unroll
    for (int ks = 0; ks < 4; ks++) {
      bf16x8 bfr = *(const bf16x8*)(WTf2o_p + col * NF + ks * 32 + lg * 8);
      hacc = __builtin_amdgcn_mfma_f32_16x16x32_bf16(cfr[ks], bfr, hacc, 0, 0, 0);
    }
    float bv = bf2o_p[col];
    #pragma unroll
    for (int r = 0; r < 4; r++)
      hLDS[(4 * lg + r) * 132 + col] = __float2bfloat16(sspf(hacc[r] + bv));
    __syncthreads();
    bf16x8 hfr[4];
    #pragma unroll
    for (int ks = 0; ks < 4; ks++)
      hfr[ks] = *(const bf16x8*)&hLDS[lr * 132 + ks * 32 + lg * 8];
    f32x4 vacc = (f32x4){0.f, 0.f, 0.f, 0.f};
    #pragma unroll
    for (int ks = 0; ks < 4; ks++) {
      bf16x8 bfr = *(const bf16x8*)(WTd_p + col * NF + ks * 32 + lg * 8);
      vacc = __builtin_amdgcn_mfma_f32_16x16x32_bf16(hfr[ks], bfr, vacc, 0, 0, 0);
    }
    float bdv = bd_p[col];
    #pragma unroll
    for (int r = 0; r < 4; r++) {
      int row = rbase + 4 * lg + r;
      float xv = xg[row * NF + col] + vacc[r] + bdv + Nb[row * NF + col];
      xout[row * NF + col] = xv;
      xLDS[(4 * lg + r) * 133 + col] = xv;
    }
    __syncthreads();
  } else {
    int rr = tid >> 5, c0 = (tid & 31) * 4;
    int row = rbase + rr;
    float4 a = *(const float4*)&emb[Z[row] * NF + c0];
    *(float4*)&xout[row * NF + c0] = a;
    xLDS[rr * 133 + c0 + 0] = a.x; xLDS[rr * 133 + c0 + 1] = a.y;
    xLDS[rr * 133 + c0 + 2] = a.z; xLDS[rr * 133 + c0 + 3] = a.w;
    __syncthreads();
  }

  // phase B: 8 waves = 4 projections x 2 col-halves
  int z = w & 3, half = w >> 2;
  const __hip_bfloat16* WT = WTl + ((z == 0) ? 0 : (z + 2)) * (NF * NF);
  float am = (z > 0) ? amask[rbase + lr] : 1.0f;
  bf16x8 afr[4];
  #pragma unroll
  for (int ks = 0; ks < 4; ks++) {
    int k0 = ks * 32 + lg * 8;
    bf16x8 t;
    #pragma unroll
    for (int jj = 0; jj < 8; jj++)
      t[jj] = (short)f2bf(xLDS[lr * 133 + k0 + jj] * am);
    afr[ks] = t;
  }

  f32x4 acc[4];
  #pragma unroll
  for (int t = 0; t < 4; t++) acc[t] = (f32x4){0.f, 0.f, 0.f, 0.f};
  #pragma unroll
  for (int ks = 0; ks < 4; ks++)
    #pragma unroll
    for (int t = 0; t < 4; t++) {
      int nt = half * 4 + t;
      bf16x8 bfr = *(const bf16x8*)(WT + (nt * 16 + lr) * NF + ks * 32 + lg * 8);
      acc[t] = __builtin_amdgcn_mfma_f32_16x16x32_bf16(afr[ks], bfr, acc[t], 0, 0, 0);
    }

  if (z < 3) {
    __hip_bfloat16* out = (z == 0) ? ybf : (z == 1) ? Qw : Kw;
    #pragma unroll
    for (int t = 0; t < 4; t++) {
      int col = (half * 4 + t) * 16 + lr;
      #pragma unroll
      for (int r = 0; r < 4; r++) {
        int orow = rbase + lg * 4 + r;
        float o = acc[t][r];
        if (z > 0) o = sspf(o);
        out[orow * NF + col] = __float2bfloat16(o);
      }
    }
  } else {
    int b = blockIdx.x >> 4;
    int ar0 = (blockIdx.x & 15) * 16 + lg * 4;
    #pragma unroll
    for (int t = 0; t < 4; t++) {
      int col = (half * 4 + t) * 16 + lr;
      #pragma unroll
      for (int r = 0; r < 4; r++)
        VwT[(b * NF + col) * NA + ar0 + r] = __float2bfloat16(sspf(acc[t][r]));
    }
  }
}

// ---------------- fa: blocks<4096 filter, else attn-core -> Nb ----------------
__global__ __launch_bounds__(256) void k_fa(
    const __hip_bfloat16* __restrict__ ybf, const int* __restrict__ nbrs,
    const float* __restrict__ pos, const float* __restrict__ nmask,
    const __hip_bfloat16* __restrict__ Wfb_l, float* __restrict__ cOut,
    const __hip_bfloat16* __restrict__ Qw, const __hip_bfloat16* __restrict__ Kw,
    const __hip_bfloat16* __restrict__ VwT, const float* __restrict__ amask,
    float* __restrict__ Nb) {
  __shared__ char smem[8832];
  int tid = threadIdx.x;
  int lane = tid & 63, w = tid >> 6, lr = lane & 15, lg = lane >> 4;

  if (blockIdx.x < 4096) {
    // ================= filter =================
    __hip_bfloat16* FF  = (__hip_bfloat16*)smem;            // [64][40]  5120 B
    float (*d3l)[4]     = (float(*)[4])(smem + 5120);       // [64][4]   1024 B
    int* jl             = (int*)(smem + 6144);              // [64]       256 B
    int atom = blockIdx.x, brow = atom & ~(NA - 1);
    const unsigned short* yu = (const unsigned short*)ybf;

    {
      int n = tid & 63;
      int j = nbrs[atom * NNBH + n];
      float px = pos[(brow + j) * 3 + 0] - pos[atom * 3 + 0];
      float py = pos[(brow + j) * 3 + 1] - pos[atom * 3 + 1];
      float pz = pos[(brow + j) * 3 + 2] - pos[atom * 3 + 2];
      float m = nmask[atom * NNBH + n];
      float r = sqrtf(px * px + py * py + pz * pz + 1e-12f) * m;
      float inv = 1.0f / (r + 1e-9f);
      float fc = (r < 5.0f) ? (0.5f * cosf(0.62831853071795865f * r) + 0.5f) * m : 0.0f;
      float xe = expf(-r);
      float l1 = log2f(xe + 1e-10f);
      float l2 = log2f(1.0f - xe + 1e-10f);
      if (tid < NNBH) {
        jl[n] = (brow + j) * NF;
        d3l[n][0] = 0.f;
        d3l[n][1] = px * inv;
        d3l[n][2] = py * inv;
        d3l[n][3] = pz * inv;
      }
      int kq = tid >> 6;
      bf16x8 v;
      #pragma unroll
      for (int j8 = 0; j8 < 8; j8++) {
        int k = kq * 8 + j8;
        float val = 0.f;
        if (k < NK)
          val = BINOM_C[k] * exp2f((float)k * l1 + (float)(24 - k) * l2) * fc;
        v[j8] = (short)f2bf(val);
      }
      *(bf16x8*)&FF[n * 40 + kq * 8] = v;
    }
    __syncthreads();

    bf16x8 af[4];
    #pragma unroll
    for (int mt = 0; mt < 4; mt++)
      af[mt] = *(bf16x8*)&FF[(16 * mt + lr) * 40 + lg * 8];

    f32x4 as_[4][2], ap_[4][2];
    #pragma unroll
    for (int mt = 0; mt < 4; mt++)
      #pragma unroll
      for (int nt2 = 0; nt2 < 2; nt2++) {
        as_[mt][nt2] = (f32x4){0.f, 0.f, 0.f, 0.f};
        ap_[mt][nt2] = (f32x4){0.f, 0.f, 0.f, 0.f};
      }
    #pragma unroll
    for (int nt2 = 0; nt2 < 2; nt2++) {
      int col = 32 * w + 16 * nt2 + lr;
      bf16x8 bs = *(const bf16x8*)&Wfb_l[col * 32 + lg * 8];
      bf16x8 bp = *(const bf16x8*)&Wfb_l[(128 + col) * 32 + lg * 8];
      #pragma unroll
      for (int mt = 0; mt < 4; mt++) {
        as_[mt][nt2] = __builtin_amdgcn_mfma_f32_16x16x32_bf16(af[mt], bs, as_[mt][nt2], 0, 0, 0);
        ap_[mt][nt2] = __builtin_amdgcn_mfma_f32_16x16x32_bf16(af[mt], bp, ap_[mt][nt2], 0, 0, 0);
      }
    }

    // contraction: preload all 32 yj values (independent L2 loads in flight),
    // then scalar FMA chain (R12 codegen).
    int rb[4][4];
    #pragma unroll
    for (int mt = 0; mt < 4; mt++)
      #pragma unroll
      for (int r = 0; r < 4; r++)
        rb[mt][r] = jl[16 * mt + 4 * lg + r];
    int f0 = 32 * w + lr, f1 = f0 + 16;

    float yv0a[4][4], yv1a[4][4];
    #pragma unroll
    for (int mt = 0; mt < 4; mt++)
      #pragma unroll
      for (int r = 0; r < 4; r++) {
        unsigned short u0 = yu[rb[mt][r] + f0];
        unsigned short u1 = yu[rb[mt][r] + f1];
        yv0a[mt][r] = __bfloat162float(*(__hip_bfloat16*)&u0);
        yv1a[mt][r] = __bfloat162float(*(__hip_bfloat16*)&u1);
      }

    float qs[2] = {0.f, 0.f}, q1[2] = {0.f, 0.f}, q2[2] = {0.f, 0.f}, q3[2] = {0.f, 0.f};
    #pragma unroll
    for (int mt = 0; mt < 4; mt++) {
      #pragma unroll
      for (int r = 0; r < 4; r++) {
        int n = 16 * mt + 4 * lg + r;
        float4 dv = *(const float4*)&d3l[n][0];
        float yv0 = yv0a[mt][r];
        float yv1 = yv1a[mt][r];
        qs[0] += yv0 * as_[mt][0][r];
        qs[1] += yv1 * as_[mt][1][r];
        float pw0 = yv0 * ap_[mt][0][r];
        float pw1 = yv1 * ap_[mt][1][r];
        q1[0] += dv.y * pw0;  q1[1] += dv.y * pw1;
        q2[0] += dv.z * pw0;  q2[1] += dv.z * pw1;
        q3[0] += dv.w * pw0;  q3[1] += dv.w * pw1;
      }
    }
    #pragma unroll
    for (int nt2 = 0; nt2 < 2; nt2++) {
      float a = qs[nt2], b1 = q1[nt2], b2 = q2[nt2], b3 = q3[nt2];
      a  += __shfl_xor(a, 16);  a  += __shfl_xor(a, 32);
      b1 += __shfl_xor(b1, 16); b1 += __shfl_xor(b1, 32);
      b2 += __shfl_xor(b2, 16); b2 += __shfl_xor(b2, 32);
      b3 += __shfl_xor(b3, 16); b3 += __shfl_xor(b3, 32);
      if (lg == 0)
        cOut[atom * NF + 32 * w + 16 * nt2 + lr] = a + b1 * b1 + b2 * b2 + b3 * b3;
    }
  } else {
    // ================= attn-core -> Nb =================
    __hip_bfloat16* Plds = (__hip_bfloat16*)smem;           // [16][260] 8320 B
    float* mwl = (float*)(smem + 8320);                     // [4][16]
    float* swl = (float*)(smem + 8576);                     // [4][16]
    int bb = blockIdx.x - 4096;
    int b = bb >> 4, qt = bb & 15;
    int qbase = b * NA + qt * 16;
    const float scale = 0.08838834764831845f;

    bf16x8 qf[4];
    #pragma unroll
    for (int ks = 0; ks < 4; ks++)
      qf[ks] = *(const bf16x8*)&Qw[(qbase + lr) * NF + ks * 32 + lg * 8];

    f32x4 sacc[4];
    #pragma unroll
    for (int ntc = 0; ntc < 4; ntc++) sacc[ntc] = (f32x4){0.f, 0.f, 0.f, 0.f};
    #pragma unroll
    for (int ks = 0; ks < 4; ks++)
      #pragma unroll
      for (int ntc = 0; ntc < 4; ntc++) {
        bf16x8 kf = *(const bf16x8*)&Kw[(b * NA + w * 64 + ntc * 16 + lr) * NF + ks * 32 + lg * 8];
        sacc[ntc] = __builtin_amdgcn_mfma_f32_16x16x32_bf16(qf[ks], kf, sacc[ntc], 0, 0, 0);
      }

    float kam[4];
    #pragma unroll
    for (int ntc = 0; ntc < 4; ntc++)
      kam[ntc] = (1.0f - amask[b * NA + w * 64 + ntc * 16 + lr]) * (-1e9f);

    #pragma unroll
    for (int r = 0; r < 4; r++) {
      float lv[4], cm = -1e30f;
      #pragma unroll
      for (int ntc = 0; ntc < 4; ntc++) {
        lv[ntc] = sacc[ntc][r] * scale + kam[ntc];
        cm = fmaxf(cm, lv[ntc]);
      }
      cm = fmaxf(cm, __shfl_xor(cm, 1)); cm = fmaxf(cm, __shfl_xor(cm, 2));
      cm = fmaxf(cm, __shfl_xor(cm, 4)); cm = fmaxf(cm, __shfl_xor(cm, 8));
      float ps = 0.f;
      #pragma unroll
      for (int ntc = 0; ntc < 4; ntc++) {
        float pp = expf(lv[ntc] - cm);
        Plds[(4 * lg + r) * 260 + w * 64 + ntc * 16 + lr] = __float2bfloat16(pp);
        ps += pp;
      }
      ps += __shfl_xor(ps, 1); ps += __shfl_xor(ps, 2);
      ps += __shfl_xor(ps, 4); ps += __shfl_xor(ps, 8);
      if (lr == 0) {
        mwl[w * 16 + 4 * lg + r] = cm;
        swl[w * 16 + 4 * lg + r] = ps;
      }
    }
    __syncthreads();

    float ec[4][4], inv_[4];
    #pragma unroll
    for (int r = 0; r < 4; r++) {
      int row = 4 * lg + r;
      float m0 = mwl[row], m1 = mwl[16 + row], m2 = mwl[32 + row], m3 = mwl[48 + row];
      float M = fmaxf(fmaxf(m0, m1), fmaxf(m2, m3));
      float e0 = expf(m0 - M), e1 = expf(m1 - M), e2 = expf(m2 - M), e3 = expf(m3 - M);
      ec[0][r] = e0; ec[1][r] = e1; ec[2][r] = e2; ec[3][r] = e3;
      float s = swl[row] * e0 + swl[16 + row] * e1 + swl[32 + row] * e2 + swl[48 + row] * e3;
      inv_[r] = amask[qbase + row] / s;
    }

    f32x4 O[2];
    O[0] = (f32x4){0.f, 0.f, 0.f, 0.f};
    O[1] = (f32x4){0.f, 0.f, 0.f, 0.f};
    #pragma unroll
    for (int c = 0; c < 4; c++) {
      bf16x8 pf[2];
      #pragma unroll
      for (int s2 = 0; s2 < 2; s2++)
        pf[s2] = *(const bf16x8*)&Plds[lr * 260 + c * 64 + s2 * 32 + lg * 8];
      f32x4 tc[2];
      tc[0] = (f32x4){0.f, 0.f, 0.f, 0.f};
      tc[1] = (f32x4){0.f, 0.f, 0.f, 0.f};
      #pragma unroll
      for (int s2 = 0; s2 < 2; s2++)
        #pragma unroll
        for (int j = 0; j < 2; j++) {
          bf16x8 vf = *(const bf16x8*)&VwT[(b * NF + (2 * w + j) * 16 + lr) * NA + c * 64 + s2 * 32 + lg * 8];
          tc[j] = __builtin_amdgcn_mfma_f32_16x16x32_bf16(pf[s2], vf, tc[j], 0, 0, 0);
        }
      #pragma unroll
      for (int j = 0; j < 2; j++)
        #pragma unroll
        for (int r = 0; r < 4; r++)
          O[j][r] += ec[c][r] * tc[j][r];
    }

    #pragma unroll
    for (int r = 0; r < 4; r++) {
      int q = qbase + 4 * lg + r;
      #pragma unroll
      for (int j = 0; j < 2; j++) {
        int col = (2 * w + j) * 16 + lr;
        Nb[q * NF + col] = O[j][r] * inv_[r];
      }
    }
  }
}

// ---------------- final: hv(L2) + residual -> x (512 thr) ----------------
__global__ __launch_bounds__(512) void k_final(
    const float* __restrict__ Cb, const float* __restrict__ Nb,
    const __hip_bfloat16* __restrict__ WTf2o_p, const float* __restrict__ bf2o_p,
    const __hip_bfloat16* __restrict__ WTd_p, const float* __restrict__ bd_p,
    float* __restrict__ x) {
  __shared__ __hip_bfloat16 hLDS[16 * 132];
  int tid = threadIdx.x;
  int w = tid >> 6, ln = tid & 63, lr = ln & 15, lg = ln >> 4;
  int rbase = blockIdx.x * 16;
  int col = w * 16 + lr;

  bf16x8 cfr[4];
  const float* cr = Cb + (rbase + lr) * NF;
  #pragma unroll
  for (int ks = 0; ks < 4; ks++) {
    int k0 = ks * 32 + lg * 8;
    float4 a = *(const float4*)&cr[k0];
    float4 c = *(const float4*)&cr[k0 + 4];
    bf16x8 t;
    t[0] = (short)f2bf(a.x); t[1] = (short)f2bf(a.y);
    t[2] = (short)f2bf(a.z); t[3] = (short)f2bf(a.w);
    t[4] = (short)f2bf(c.x); t[5] = (short)f2bf(c.y);
    t[6] = (short)f2bf(c.z); t[7] = (short)f2bf(c.w);
    cfr[ks] = t;
  }
  f32x4 hacc = (f32x4){0.f, 0.f, 0.f, 0.f};
  #pragma unroll
  for (int ks = 0; ks < 4; ks++) {
    bf16x8 bfr = *(const bf16x8*)(WTf2o_p + col * NF + ks * 32 + lg * 8);
    hacc = __builtin_amdgcn_mfma_f32_16x16x32_bf16(cfr[ks], bfr, hacc, 0, 0, 0);
  }
  float bv = bf2o_p[col];
  #pragma unroll
  for (int r = 0; r < 4; r++)
    hLDS[(4 * lg + r) * 132 + col] = __float2bfloat16(sspf(hacc[r] + bv));
  __syncthreads();
  bf16x8 hfr[4];
  #pragma unroll
  for (int ks = 0; ks < 4; ks++)
    hfr[ks] = *(const bf16x8*)&hLDS[lr * 132 + ks * 32 + lg * 8];
  f32x4 vacc = (f32x4){0.f, 0.f, 0.f, 0.f};
  #pragma unroll
  for (int ks = 0; ks < 4; ks++) {
    bf16x8 bfr = *(const bf16x8*)(WTd_p + col * NF + ks * 32 + lg * 8);
    vacc = __builtin_amdgcn_mfma_f32_16x16x32_bf16(hfr[ks], bfr, vacc, 0, 0, 0);
  }
  float bdv = bd_p[col];
  #pragma unroll
  for (int r = 0; r < 4; r++) {
    int row = rbase + 4 * lg + r;
    x[row * NF + col] += vacc[r] + bdv + Nb[row * NF + col];
  }
}

// ---------------- host launch ----------------
extern "C" void kernel_launch(void* const* d_in, const int* in_sizes, int n_in,
                              void* d_out, int out_size, void* d_ws, size_t ws_size,
                              hipStream_t stream) {
  const float* pos   = (const float*)d_in[0];
  const float* nmask = (const float*)d_in[1];
  const float* amask = (const float*)d_in[2];
  const float* emb   = (const float*)d_in[3];
  const float* Wfs   = (const float*)d_in[4];
  const float* Wfp   = (const float*)d_in[5];
  const float* Win   = (const float*)d_in[6];
  const float* Wf2o  = (const float*)d_in[7];
  const float* bf2o  = (const float*)d_in[8];
  const float* Wd    = (const float*)d_in[9];
  const float* bd    = (const float*)d_in[10];
  const float* Wq    = (const float*)d_in[11];
  const float* Wk    = (const float*)d_in[12];
  const float* Wv    = (const float*)d_in[13];
  const int*   Z     = (const int*)d_in[14];
  const int*   nbrs  = (const int*)d_in[15];

  float* x = (float*)d_out;
  float* wsf = (float*)d_ws;
  const int S = NATOM * NF;                               // 524288
  float* Cb = wsf;                                        // S f32
  float* Nb = wsf + S;                                    // S f32
  __hip_bfloat16* ybf = (__hip_bfloat16*)(wsf + 2 * S);
  __hip_bfloat16* Qw  = ybf + S;
  __hip_bfloat16* Kw  = Qw + S;
  __hip_bfloat16* VwT = Kw + S;                           // [b][f][row]
  __hip_bfloat16* WT  = VwT + S;                          // 18*16384 bf16
  __hip_bfloat16* Wfb = WT + 18 * 16384;                  // 24576 bf16

  k_init<<<dim3(1248), dim3(256), 0, stream>>>(
      Win, Wf2o, Wd, Wq, Wk, Wv, Wfs, Wfp, WT, Wfb);

  for (int l = 0; l < 3; l++) {
    const __hip_bfloat16* WTl = WT + l * 6 * 16384;
    if (l == 0)
      k_proj<0><<<dim3(256), dim3(512), 0, stream>>>(
          nullptr, Z, emb, nullptr, nullptr, nullptr, nullptr, nullptr, nullptr,
          amask, WTl, x, ybf, Qw, Kw, VwT);
    else {
      const __hip_bfloat16* WTp = WT + (l - 1) * 6 * 16384;
      k_proj<1><<<dim3(256), dim3(512), 0, stream>>>(
          x, nullptr, nullptr, Cb, Nb, WTp + 16384, bf2o + (l - 1) * NF,
          WTp + 2 * 16384, bd + (l - 1) * NF, amask, WTl, x, ybf, Qw, Kw, VwT);
    }
    k_fa<<<dim3(4096 + 256), dim3(256), 0, stream>>>(
        ybf, nbrs, pos, nmask, Wfb + l * 8192, Cb, Qw, Kw, VwT, amask, Nb);
  }
  const __hip_bfloat16* WT2 = WT + 2 * 6 * 16384;
  k_final<<<dim3(256), dim3(512), 0, stream>>>(
      Cb, Nb, WT2 + 16384, bf2o + 2 * NF, WT2 + 2 * 16384, bd + 2 * NF, x);
}

// Round 16
// 154.749 us; speedup vs baseline: 1.2530x; 1.2351x over previous
//
#include <hip/hip_runtime.h>
#include <hip/hip_bf16.h>
#include <math.h>

// TbpNet: B=16, A=256, NBH=64, F=128, K=25, L=3.
// R15: exact R12 source (166.8us proven; R13/R14 contraction rewrites both
//      regressed) + XCD-aware block swizzle in k_fa: each XCD owns 2 batches
//      so the y-row gather working set (128 KB) lives in that XCD's L2.
#define NB   16
#define NA   256
#define NNBH 64
#define NF   128
#define NK   25
#define NATOM (NB*NA)   // 4096

typedef __attribute__((ext_vector_type(4))) float f32x4;
typedef __attribute__((ext_vector_type(8))) short bf16x8;

__device__ __constant__ float BINOM_C[25] = {
  1.f, 24.f, 276.f, 2024.f, 10626.f, 42504.f, 134596.f, 346104.f,
  735471.f, 1307504.f, 1961256.f, 2496144.f, 2704156.f, 2496144.f,
  1961256.f, 1307504.f, 735471.f, 346104.f, 134596.f, 42504.f,
  10626.f, 2024.f, 276.f, 24.f, 1.f
};

__device__ __forceinline__ float sspf(float x) {
  float t = (x > 20.f) ? x : log1pf(expf(x));
  return t - 0.69314718055994531f;
}
__device__ __forceinline__ unsigned short f2bf(float x) {
  __hip_bfloat16 h = __float2bfloat16(x);
  return *(unsigned short*)&h;
}

// ---------------- init: WT prep + Wfb prep ----------------
__global__ __launch_bounds__(256) void k_init(
    const float* __restrict__ Win, const float* __restrict__ Wf2o,
    const float* __restrict__ Wd, const float* __restrict__ Wq,
    const float* __restrict__ Wk, const float* __restrict__ Wv,
    const float* __restrict__ Wfs, const float* __restrict__ Wfp,
    __hip_bfloat16* __restrict__ WT, __hip_bfloat16* __restrict__ Wfb) {
  int bid = blockIdx.x, tid = threadIdx.x;
  if (bid < 1152) {
    int idx = bid * 256 + tid;               // 18*16384
    int e = idx & 16383; int m = idx >> 14;
    int l = m / 6, wsel = m - l * 6;
    const float* src = (wsel == 0) ? Win : (wsel == 1) ? Wf2o : (wsel == 2) ? Wd
                      : (wsel == 3) ? Wq : (wsel == 4) ? Wk : Wv;
    int k = e >> 7, col = e & 127;
    WT[m * 16384 + col * 128 + k] = __float2bfloat16(src[l * NF * NF + k * NF + col]);
  } else {
    int idx = (bid - 1152) * 256 + tid;      // 24576
    int k = idx & 31, f = (idx >> 5) & 127, s = (idx >> 12) & 1, l = idx >> 13;
    float v = 0.f;
    if (k < NK) v = (s ? Wfp : Wfs)[l * NK * NF + k * NF + f];
    Wfb[idx] = __float2bfloat16(v);          // [l][s][f][k]
  }
}

// ---------------- proj: 512 thr. [phase A: hv(prev)+residual] + QKVY ----------
template<int HV>
__global__ __launch_bounds__(512) void k_proj(
    const float* __restrict__ xg, const int* __restrict__ Z,
    const float* __restrict__ emb,
    const float* __restrict__ Cb, const float* __restrict__ Nb,
    const __hip_bfloat16* __restrict__ WTf2o_p, const float* __restrict__ bf2o_p,
    const __hip_bfloat16* __restrict__ WTd_p, const float* __restrict__ bd_p,
    const float* __restrict__ amask, const __hip_bfloat16* __restrict__ WTl,
    float* __restrict__ xout,
    __hip_bfloat16* __restrict__ ybf, __hip_bfloat16* __restrict__ Qw,
    __hip_bfloat16* __restrict__ Kw, __hip_bfloat16* __restrict__ VwT) {
  __shared__ __hip_bfloat16 hLDS[16 * 132];
  __shared__ float xLDS[16 * 133];
  int tid = threadIdx.x;
  int w = tid >> 6, ln = tid & 63, lr = ln & 15, lg = ln >> 4;
  int rbase = blockIdx.x * 16;

  if (HV) {
    bf16x8 cfr[4];
    const float* cr = Cb + (rbase + lr) * NF;
    #pragma unroll
    for (int ks = 0; ks < 4; ks++) {
      int k0 = ks * 32 + lg * 8;
      float4 a = *(const float4*)&cr[k0];
      float4 c = *(const float4*)&cr[k0 + 4];
      bf16x8 t;
      t[0] = (short)f2bf(a.x); t[1] = (short)f2bf(a.y);
      t[2] = (short)f2bf(a.z); t[3] = (short)f2bf(a.w);
      t[4] = (short)f2bf(c.x); t[5] = (short)f2bf(c.y);
      t[6] = (short)f2bf(c.z); t[7] = (short)f2bf(c.w);
      cfr[ks] = t;
    }
    int col = w * 16 + lr;
    f32x4 hacc = (f32x4){0.f, 0.f, 0.f, 0.f};
    #pragma unroll
    for (int ks = 0; ks < 4; ks++) {
      bf16x8 bfr = *(const bf16x8*)(WTf2o_p + col * NF + ks * 32 + lg * 8);
      hacc = __builtin_amdgcn_mfma_f32_16x16x32_bf16(cfr[ks], bfr, hacc, 0, 0, 0);
    }
    float bv = bf2o_p[col];
    #pragma unroll
    for (int r = 0; r < 4; r++)
      hLDS[(4 * lg + r) * 132 + col] = __float2bfloat16(sspf(hacc[r] + bv));
    __syncthreads();
    bf16x8 hfr[4];
    #pragma unroll
    for (int ks = 0; ks < 4; ks++)
      hfr[ks] = *(const bf16x8*)&hLDS[lr * 132 + ks * 32 + lg * 8];
    f32x4 vacc = (f32x4){0.f, 0.f, 0.f, 0.f};
    #pragma unroll
    for (int ks = 0; ks < 4; ks++) {
      bf16x8 bfr = *(const bf16x8*)(WTd_p + col * NF + ks * 32 + lg * 8);
      vacc = __builtin_amdgcn_mfma_f32_16x16x32_bf16(hfr[ks], bfr, vacc, 0, 0, 0);
    }
    float bdv = bd_p[col];
    #pragma unroll
    for (int r = 0; r < 4; r++) {
      int row = rbase + 4 * lg + r;
      float xv = xg[row * NF + col] + vacc[r] + bdv + Nb[row * NF + col];
      xout[row * NF + col] = xv;
      xLDS[(4 * lg + r) * 133 + col] = xv;
    }
    __syncthreads();
  } else {
    int rr = tid >> 5, c0 = (tid & 31) * 4;
    int row = rbase + rr;
    float4 a = *(const float4*)&emb[Z[row] * NF + c0];
    *(float4*)&xout[row * NF + c0] = a;
    xLDS[rr * 133 + c0 + 0] = a.x; xLDS[rr * 133 + c0 + 1] = a.y;
    xLDS[rr * 133 + c0 + 2] = a.z; xLDS[rr * 133 + c0 + 3] = a.w;
    __syncthreads();
  }

  // phase B: 8 waves = 4 projections x 2 col-halves
  int z = w & 3, half = w >> 2;
  const __hip_bfloat16* WT = WTl + ((z == 0) ? 0 : (z + 2)) * (NF * NF);
  float am = (z > 0) ? amask[rbase + lr] : 1.0f;
  bf16x8 afr[4];
  #pragma unroll
  for (int ks = 0; ks < 4; ks++) {
    int k0 = ks * 32 + lg * 8;
    bf16x8 t;
    #pragma unroll
    for (int jj = 0; jj < 8; jj++)
      t[jj] = (short)f2bf(xLDS[lr * 133 + k0 + jj] * am);
    afr[ks] = t;
  }

  f32x4 acc[4];
  #pragma unroll
  for (int t = 0; t < 4; t++) acc[t] = (f32x4){0.f, 0.f, 0.f, 0.f};
  #pragma unroll
  for (int ks = 0; ks < 4; ks++)
    #pragma unroll
    for (int t = 0; t < 4; t++) {
      int nt = half * 4 + t;
      bf16x8 bfr = *(const bf16x8*)(WT + (nt * 16 + lr) * NF + ks * 32 + lg * 8);
      acc[t] = __builtin_amdgcn_mfma_f32_16x16x32_bf16(afr[ks], bfr, acc[t], 0, 0, 0);
    }

  if (z < 3) {
    __hip_bfloat16* out = (z == 0) ? ybf : (z == 1) ? Qw : Kw;
    #pragma unroll
    for (int t = 0; t < 4; t++) {
      int col = (half * 4 + t) * 16 + lr;
      #pragma unroll
      for (int r = 0; r < 4; r++) {
        int orow = rbase + lg * 4 + r;
        float o = acc[t][r];
        if (z > 0) o = sspf(o);
        out[orow * NF + col] = __float2bfloat16(o);
      }
    }
  } else {
    int b = blockIdx.x >> 4;
    int ar0 = (blockIdx.x & 15) * 16 + lg * 4;
    #pragma unroll
    for (int t = 0; t < 4; t++) {
      int col = (half * 4 + t) * 16 + lr;
      #pragma unroll
      for (int r = 0; r < 4; r++)
        VwT[(b * NF + col) * NA + ar0 + r] = __float2bfloat16(sspf(acc[t][r]));
    }
  }
}

// ---------------- fa: filter / attn-core, XCD-swizzled block map ----------------
__global__ __launch_bounds__(256) void k_fa(
    const __hip_bfloat16* __restrict__ ybf, const int* __restrict__ nbrs,
    const float* __restrict__ pos, const float* __restrict__ nmask,
    const __hip_bfloat16* __restrict__ Wfb_l, float* __restrict__ cOut,
    const __hip_bfloat16* __restrict__ Qw, const __hip_bfloat16* __restrict__ Kw,
    const __hip_bfloat16* __restrict__ VwT, const float* __restrict__ amask,
    float* __restrict__ Nb) {
  __shared__ char smem[8832];
  int tid = threadIdx.x;
  int lane = tid & 63, w = tid >> 6, lr = lane & 15, lg = lane >> 4;

  if (blockIdx.x < 4096) {
    // ================= filter =================
    // XCD swizzle: XCD r (= bid%8) handles atoms [512r, 512r+512) = batches
    // {2r, 2r+1}; their y-rows (128 KB) stay resident in that XCD's L2.
    int bid = blockIdx.x;
    int atom = ((bid & 7) << 9) + (bid >> 3);
    __hip_bfloat16* FF  = (__hip_bfloat16*)smem;            // [64][40]  5120 B
    float (*d3l)[4]     = (float(*)[4])(smem + 5120);       // [64][4]   1024 B
    int* jl             = (int*)(smem + 6144);              // [64]       256 B
    int brow = atom & ~(NA - 1);
    const unsigned short* yu = (const unsigned short*)ybf;

    {
      int n = tid & 63;
      int j = nbrs[atom * NNBH + n];
      float px = pos[(brow + j) * 3 + 0] - pos[atom * 3 + 0];
      float py = pos[(brow + j) * 3 + 1] - pos[atom * 3 + 1];
      float pz = pos[(brow + j) * 3 + 2] - pos[atom * 3 + 2];
      float m = nmask[atom * NNBH + n];
      float r = sqrtf(px * px + py * py + pz * pz + 1e-12f) * m;
      float inv = 1.0f / (r + 1e-9f);
      float fc = (r < 5.0f) ? (0.5f * cosf(0.62831853071795865f * r) + 0.5f) * m : 0.0f;
      float xe = expf(-r);
      float l1 = log2f(xe + 1e-10f);
      float l2 = log2f(1.0f - xe + 1e-10f);
      if (tid < NNBH) {
        jl[n] = (brow + j) * NF;
        d3l[n][0] = 0.f;
        d3l[n][1] = px * inv;
        d3l[n][2] = py * inv;
        d3l[n][3] = pz * inv;
      }
      int kq = tid >> 6;
      bf16x8 v;
      #pragma unroll
      for (int j8 = 0; j8 < 8; j8++) {
        int k = kq * 8 + j8;
        float val = 0.f;
        if (k < NK)
          val = BINOM_C[k] * exp2f((float)k * l1 + (float)(24 - k) * l2) * fc;
        v[j8] = (short)f2bf(val);
      }
      *(bf16x8*)&FF[n * 40 + kq * 8] = v;
    }
    __syncthreads();

    bf16x8 af[4];
    #pragma unroll
    for (int mt = 0; mt < 4; mt++)
      af[mt] = *(bf16x8*)&FF[(16 * mt + lr) * 40 + lg * 8];

    f32x4 as_[4][2], ap_[4][2];
    #pragma unroll
    for (int mt = 0; mt < 4; mt++)
      #pragma unroll
      for (int nt2 = 0; nt2 < 2; nt2++) {
        as_[mt][nt2] = (f32x4){0.f, 0.f, 0.f, 0.f};
        ap_[mt][nt2] = (f32x4){0.f, 0.f, 0.f, 0.f};
      }
    #pragma unroll
    for (int nt2 = 0; nt2 < 2; nt2++) {
      int col = 32 * w + 16 * nt2 + lr;
      bf16x8 bs = *(const bf16x8*)&Wfb_l[col * 32 + lg * 8];
      bf16x8 bp = *(const bf16x8*)&Wfb_l[(128 + col) * 32 + lg * 8];
      #pragma unroll
      for (int mt = 0; mt < 4; mt++) {
        as_[mt][nt2] = __builtin_amdgcn_mfma_f32_16x16x32_bf16(af[mt], bs, as_[mt][nt2], 0, 0, 0);
        ap_[mt][nt2] = __builtin_amdgcn_mfma_f32_16x16x32_bf16(af[mt], bp, ap_[mt][nt2], 0, 0, 0);
      }
    }

    // contraction: yj direct from global (coalesced u16, L2-local after swizzle)
    int rb[4][4];
    #pragma unroll
    for (int mt = 0; mt < 4; mt++)
      #pragma unroll
      for (int r = 0; r < 4; r++)
        rb[mt][r] = jl[16 * mt + 4 * lg + r];
    int f0 = 32 * w + lr, f1 = f0 + 16;

    float qs[2] = {0.f, 0.f}, q1[2] = {0.f, 0.f}, q2[2] = {0.f, 0.f}, q3[2] = {0.f, 0.f};
    #pragma unroll
    for (int mt = 0; mt < 4; mt++) {
      #pragma unroll
      for (int r = 0; r < 4; r++) {
        int n = 16 * mt + 4 * lg + r;
        float4 dv = *(const float4*)&d3l[n][0];
        unsigned short u0 = yu[rb[mt][r] + f0];
        unsigned short u1 = yu[rb[mt][r] + f1];
        float yv0 = __bfloat162float(*(__hip_bfloat16*)&u0);
        float yv1 = __bfloat162float(*(__hip_bfloat16*)&u1);
        qs[0] += yv0 * as_[mt][0][r];
        qs[1] += yv1 * as_[mt][1][r];
        float pw0 = yv0 * ap_[mt][0][r];
        float pw1 = yv1 * ap_[mt][1][r];
        q1[0] += dv.y * pw0;  q1[1] += dv.y * pw1;
        q2[0] += dv.z * pw0;  q2[1] += dv.z * pw1;
        q3[0] += dv.w * pw0;  q3[1] += dv.w * pw1;
      }
    }
    #pragma unroll
    for (int nt2 = 0; nt2 < 2; nt2++) {
      float a = qs[nt2], b1 = q1[nt2], b2 = q2[nt2], b3 = q3[nt2];
      a  += __shfl_xor(a, 16);  a  += __shfl_xor(a, 32);
      b1 += __shfl_xor(b1, 16); b1 += __shfl_xor(b1, 32);
      b2 += __shfl_xor(b2, 16); b2 += __shfl_xor(b2, 32);
      b3 += __shfl_xor(b3, 16); b3 += __shfl_xor(b3, 32);
      if (lg == 0)
        cOut[atom * NF + 32 * w + 16 * nt2 + lr] = a + b1 * b1 + b2 * b2 + b3 * b3;
    }
  } else {
    // ================= attn-core -> Nb =================
    // same batch-pair -> XCD mapping as the filter blocks
    int bb = blockIdx.x - 4096;
    bb = ((bb & 7) << 5) + (bb >> 3);
    __hip_bfloat16* Plds = (__hip_bfloat16*)smem;           // [16][260] 8320 B
    float* mwl = (float*)(smem + 8320);                     // [4][16]
    float* swl = (float*)(smem + 8576);                     // [4][16]
    int b = bb >> 4, qt = bb & 15;
    int qbase = b * NA + qt * 16;
    const float scale = 0.08838834764831845f;

    bf16x8 qf[4];
    #pragma unroll
    for (int ks = 0; ks < 4; ks++)
      qf[ks] = *(const bf16x8*)&Qw[(qbase + lr) * NF + ks * 32 + lg * 8];

    f32x4 sacc[4];
    #pragma unroll
    for (int ntc = 0; ntc < 4; ntc++) sacc[ntc] = (f32x4){0.f, 0.f, 0.f, 0.f};
    #pragma unroll
    for (int ks = 0; ks < 4; ks++)
      #pragma unroll
      for (int ntc = 0; ntc < 4; ntc++) {
        bf16x8 kf = *(const bf16x8*)&Kw[(b * NA + w * 64 + ntc * 16 + lr) * NF + ks * 32 + lg * 8];
        sacc[ntc] = __builtin_amdgcn_mfma_f32_16x16x32_bf16(qf[ks], kf, sacc[ntc], 0, 0, 0);
      }

    float kam[4];
    #pragma unroll
    for (int ntc = 0; ntc < 4; ntc++)
      kam[ntc] = (1.0f - amask[b * NA + w * 64 + ntc * 16 + lr]) * (-1e9f);

    #pragma unroll
    for (int r = 0; r < 4; r++) {
      float lv[4], cm = -1e30f;
      #pragma unroll
      for (int ntc = 0; ntc < 4; ntc++) {
        lv[ntc] = sacc[ntc][r] * scale + kam[ntc];
        cm = fmaxf(cm, lv[ntc]);
      }
      cm = fmaxf(cm, __shfl_xor(cm, 1)); cm = fmaxf(cm, __shfl_xor(cm, 2));
      cm = fmaxf(cm, __shfl_xor(cm, 4)); cm = fmaxf(cm, __shfl_xor(cm, 8));
      float ps = 0.f;
      #pragma unroll
      for (int ntc = 0; ntc < 4; ntc++) {
        float pp = expf(lv[ntc] - cm);
        Plds[(4 * lg + r) * 260 + w * 64 + ntc * 16 + lr] = __float2bfloat16(pp);
        ps += pp;
      }
      ps += __shfl_xor(ps, 1); ps += __shfl_xor(ps, 2);
      ps += __shfl_xor(ps, 4); ps += __shfl_xor(ps, 8);
      if (lr == 0) {
        mwl[w * 16 + 4 * lg + r] = cm;
        swl[w * 16 + 4 * lg + r] = ps;
      }
    }
    __syncthreads();

    float ec[4][4], inv_[4];
    #pragma unroll
    for (int r = 0; r < 4; r++) {
      int row = 4 * lg + r;
      float m0 = mwl[row], m1 = mwl[16 + row], m2 = mwl[32 + row], m3 = mwl[48 + row];
      float M = fmaxf(fmaxf(m0, m1), fmaxf(m2, m3));
      float e0 = expf(m0 - M), e1 = expf(m1 - M), e2 = expf(m2 - M), e3 = expf(m3 - M);
      ec[0][r] = e0; ec[1][r] = e1; ec[2][r] = e2; ec[3][r] = e3;
      float s = swl[row] * e0 + swl[16 + row] * e1 + swl[32 + row] * e2 + swl[48 + row] * e3;
      inv_[r] = amask[qbase + row] / s;
    }

    f32x4 O[2];
    O[0] = (f32x4){0.f, 0.f, 0.f, 0.f};
    O[1] = (f32x4){0.f, 0.f, 0.f, 0.f};
    #pragma unroll
    for (int c = 0; c < 4; c++) {
      bf16x8 pf[2];
      #pragma unroll
      for (int s2 = 0; s2 < 2; s2++)
        pf[s2] = *(const bf16x8*)&Plds[lr * 260 + c * 64 + s2 * 32 + lg * 8];
      f32x4 tc[2];
      tc[0] = (f32x4){0.f, 0.f, 0.f, 0.f};
      tc[1] = (f32x4){0.f, 0.f, 0.f, 0.f};
      #pragma unroll
      for (int s2 = 0; s2 < 2; s2++)
        #pragma unroll
        for (int j = 0; j < 2; j++) {
          bf16x8 vf = *(const bf16x8*)&VwT[(b * NF + (2 * w + j) * 16 + lr) * NA + c * 64 + s2 * 32 + lg * 8];
          tc[j] = __builtin_amdgcn_mfma_f32_16x16x32_bf16(pf[s2], vf, tc[j], 0, 0, 0);
        }
      #pragma unroll
      for (int j = 0; j < 2; j++)
        #pragma unroll
        for (int r = 0; r < 4; r++)
          O[j][r] += ec[c][r] * tc[j][r];
    }

    #pragma unroll
    for (int r = 0; r < 4; r++) {
      int q = qbase + 4 * lg + r;
      #pragma unroll
      for (int j = 0; j < 2; j++) {
        int col = (2 * w + j) * 16 + lr;
        Nb[q * NF + col] = O[j][r] * inv_[r];
      }
    }
  }
}

// ---------------- final: hv(L2) + residual -> x (512 thr) ----------------
__global__ __launch_bounds__(512) void k_final(
    const float* __restrict__ Cb, const float* __restrict__ Nb,
    const __hip_bfloat16* __restrict__ WTf2o_p, const float* __restrict__ bf2o_p,
    const __hip_bfloat16* __restrict__ WTd_p, const float* __restrict__ bd_p,
    float* __restrict__ x) {
  __shared__ __hip_bfloat16 hLDS[16 * 132];
  int tid = threadIdx.x;
  int w = tid >> 6, ln = tid & 63, lr = ln & 15, lg = ln >> 4;
  int rbase = blockIdx.x * 16;
  int col = w * 16 + lr;

  bf16x8 cfr[4];
  const float* cr = Cb + (rbase + lr) * NF;
  #pragma unroll
  for (int ks = 0; ks < 4; ks++) {
    int k0 = ks * 32 + lg * 8;
    float4 a = *(const float4*)&cr[k0];
    float4 c = *(const float4*)&cr[k0 + 4];
    bf16x8 t;
    t[0] = (short)f2bf(a.x); t[1] = (short)f2bf(a.y);
    t[2] = (short)f2bf(a.z); t[3] = (short)f2bf(a.w);
    t[4] = (short)f2bf(c.x); t[5] = (short)f2bf(c.y);
    t[6] = (short)f2bf(c.z); t[7] = (short)f2bf(c.w);
    cfr[ks] = t;
  }
  f32x4 hacc = (f32x4){0.f, 0.f, 0.f, 0.f};
  #pragma unroll
  for (int ks = 0; ks < 4; ks++) {
    bf16x8 bfr = *(const bf16x8*)(WTf2o_p + col * NF + ks * 32 + lg * 8);
    hacc = __builtin_amdgcn_mfma_f32_16x16x32_bf16(cfr[ks], bfr, hacc, 0, 0, 0);
  }
  float bv = bf2o_p[col];
  #pragma unroll
  for (int r = 0; r < 4; r++)
    hLDS[(4 * lg + r) * 132 + col] = __float2bfloat16(sspf(hacc[r] + bv));
  __syncthreads();
  bf16x8 hfr[4];
  #pragma unroll
  for (int ks = 0; ks < 4; ks++)
    hfr[ks] = *(const bf16x8*)&hLDS[lr * 132 + ks * 32 + lg * 8];
  f32x4 vacc = (f32x4){0.f, 0.f, 0.f, 0.f};
  #pragma unroll
  for (int ks = 0; ks < 4; ks++) {
    bf16x8 bfr = *(const bf16x8*)(WTd_p + col * NF + ks * 32 + lg * 8);
    vacc = __builtin_amdgcn_mfma_f32_16x16x32_bf16(hfr[ks], bfr, vacc, 0, 0, 0);
  }
  float bdv = bd_p[col];
  #pragma unroll
  for (int r = 0; r < 4; r++) {
    int row = rbase + 4 * lg + r;
    x[row * NF + col] += vacc[r] + bdv + Nb[row * NF + col];
  }
}

// ---------------- host launch ----------------
extern "C" void kernel_launch(void* const* d_in, const int* in_sizes, int n_in,
                              void* d_out, int out_size, void* d_ws, size_t ws_size,
                              hipStream_t stream) {
  const float* pos   = (const float*)d_in[0];
  const float* nmask = (const float*)d_in[1];
  const float* amask = (const float*)d_in[2];
  const float* emb   = (const float*)d_in[3];
  const float* Wfs   = (const float*)d_in[4];
  const float* Wfp   = (const float*)d_in[5];
  const float* Win   = (const float*)d_in[6];
  const float* Wf2o  = (const float*)d_in[7];
  const float* bf2o  = (const float*)d_in[8];
  const float* Wd    = (const float*)d_in[9];
  const float* bd    = (const float*)d_in[10];
  const float* Wq    = (const float*)d_in[11];
  const float* Wk    = (const float*)d_in[12];
  const float* Wv    = (const float*)d_in[13];
  const int*   Z     = (const int*)d_in[14];
  const int*   nbrs  = (const int*)d_in[15];

  float* x = (float*)d_out;
  float* wsf = (float*)d_ws;
  const int S = NATOM * NF;                               // 524288
  float* Cb = wsf;                                        // S f32
  float* Nb = wsf + S;                                    // S f32
  __hip_bfloat16* ybf = (__hip_bfloat16*)(wsf + 2 * S);
  __hip_bfloat16* Qw  = ybf + S;
  __hip_bfloat16* Kw  = Qw + S;
  __hip_bfloat16* VwT = Kw + S;                           // [b][f][row]
  __hip_bfloat16* WT  = VwT + S;                          // 18*16384 bf16
  __hip_bfloat16* Wfb = WT + 18 * 16384;                  // 24576 bf16

  k_init<<<dim3(1248), dim3(256), 0, stream>>>(
      Win, Wf2o, Wd, Wq, Wk, Wv, Wfs, Wfp, WT, Wfb);

  for (int l = 0; l < 3; l++) {
    const __hip_bfloat16* WTl = WT + l * 6 * 16384;
    if (l == 0)
      k_proj<0><<<dim3(256), dim3(512), 0, stream>>>(
          nullptr, Z, emb, nullptr, nullptr, nullptr, nullptr, nullptr, nullptr,
          amask, WTl, x, ybf, Qw, Kw, VwT);
    else {
      const __hip_bfloat16* WTp = WT + (l - 1) * 6 * 16384;
      k_proj<1><<<dim3(256), dim3(512), 0, stream>>>(
          x, nullptr, nullptr, Cb, Nb, WTp + 16384, bf2o + (l - 1) * NF,
          WTp + 2 * 16384, bd + (l - 1) * NF, amask, WTl, x, ybf, Qw, Kw, VwT);
    }
    k_fa<<<dim3(4096 + 256), dim3(256), 0, stream>>>(
        ybf, nbrs, pos, nmask, Wfb + l * 8192, Cb, Qw, Kw, VwT, amask, Nb);
  }
  const __hip_bfloat16* WT2 = WT + 2 * 6 * 16384;
  k_final<<<dim3(256), dim3(512), 0, stream>>>(
      Cb, Nb, WT2 + 16384, bf2o + 2 * NF, WT2 + 2 * 16384, bd + 2 * NF, x);
}

// Round 17
// 154.360 us; speedup vs baseline: 1.2562x; 1.0025x over previous
//
#include <hip/hip_runtime.h>
#include <hip/hip_bf16.h>
#include <math.h>

// TbpNet: B=16, A=256, NBH=64, F=128, K=25, L=3.
// R16: R15 (154.7us) + attn blocks FIRST in k_fa (0..255) so their latency
//      chain overlaps the filter wave instead of running in the drain tail.
#define NB   16
#define NA   256
#define NNBH 64
#define NF   128
#define NK   25
#define NATOM (NB*NA)   // 4096

typedef __attribute__((ext_vector_type(4))) float f32x4;
typedef __attribute__((ext_vector_type(8))) short bf16x8;

__device__ __constant__ float BINOM_C[25] = {
  1.f, 24.f, 276.f, 2024.f, 10626.f, 42504.f, 134596.f, 346104.f,
  735471.f, 1307504.f, 1961256.f, 2496144.f, 2704156.f, 2496144.f,
  1961256.f, 1307504.f, 735471.f, 346104.f, 134596.f, 42504.f,
  10626.f, 2024.f, 276.f, 24.f, 1.f
};

__device__ __forceinline__ float sspf(float x) {
  float t = (x > 20.f) ? x : log1pf(expf(x));
  return t - 0.69314718055994531f;
}
__device__ __forceinline__ unsigned short f2bf(float x) {
  __hip_bfloat16 h = __float2bfloat16(x);
  return *(unsigned short*)&h;
}

// ---------------- init: WT prep + Wfb prep ----------------
__global__ __launch_bounds__(256) void k_init(
    const float* __restrict__ Win, const float* __restrict__ Wf2o,
    const float* __restrict__ Wd, const float* __restrict__ Wq,
    const float* __restrict__ Wk, const float* __restrict__ Wv,
    const float* __restrict__ Wfs, const float* __restrict__ Wfp,
    __hip_bfloat16* __restrict__ WT, __hip_bfloat16* __restrict__ Wfb) {
  int bid = blockIdx.x, tid = threadIdx.x;
  if (bid < 1152) {
    int idx = bid * 256 + tid;               // 18*16384
    int e = idx & 16383; int m = idx >> 14;
    int l = m / 6, wsel = m - l * 6;
    const float* src = (wsel == 0) ? Win : (wsel == 1) ? Wf2o : (wsel == 2) ? Wd
                      : (wsel == 3) ? Wq : (wsel == 4) ? Wk : Wv;
    int k = e >> 7, col = e & 127;
    WT[m * 16384 + col * 128 + k] = __float2bfloat16(src[l * NF * NF + k * NF + col]);
  } else {
    int idx = (bid - 1152) * 256 + tid;      // 24576
    int k = idx & 31, f = (idx >> 5) & 127, s = (idx >> 12) & 1, l = idx >> 13;
    float v = 0.f;
    if (k < NK) v = (s ? Wfp : Wfs)[l * NK * NF + k * NF + f];
    Wfb[idx] = __float2bfloat16(v);          // [l][s][f][k]
  }
}

// ---------------- proj: 512 thr. [phase A: hv(prev)+residual] + QKVY ----------
template<int HV>
__global__ __launch_bounds__(512) void k_proj(
    const float* __restrict__ xg, const int* __restrict__ Z,
    const float* __restrict__ emb,
    const float* __restrict__ Cb, const float* __restrict__ Nb,
    const __hip_bfloat16* __restrict__ WTf2o_p, const float* __restrict__ bf2o_p,
    const __hip_bfloat16* __restrict__ WTd_p, const float* __restrict__ bd_p,
    const float* __restrict__ amask, const __hip_bfloat16* __restrict__ WTl,
    float* __restrict__ xout,
    __hip_bfloat16* __restrict__ ybf, __hip_bfloat16* __restrict__ Qw,
    __hip_bfloat16* __restrict__ Kw, __hip_bfloat16* __restrict__ VwT) {
  __shared__ __hip_bfloat16 hLDS[16 * 132];
  __shared__ float xLDS[16 * 133];
  int tid = threadIdx.x;
  int w = tid >> 6, ln = tid & 63, lr = ln & 15, lg = ln >> 4;
  int rbase = blockIdx.x * 16;

  if (HV) {
    bf16x8 cfr[4];
    const float* cr = Cb + (rbase + lr) * NF;
    #pragma unroll
    for (int ks = 0; ks < 4; ks++) {
      int k0 = ks * 32 + lg * 8;
      float4 a = *(const float4*)&cr[k0];
      float4 c = *(const float4*)&cr[k0 + 4];
      bf16x8 t;
      t[0] = (short)f2bf(a.x); t[1] = (short)f2bf(a.y);
      t[2] = (short)f2bf(a.z); t[3] = (short)f2bf(a.w);
      t[4] = (short)f2bf(c.x); t[5] = (short)f2bf(c.y);
      t[6] = (short)f2bf(c.z); t[7] = (short)f2bf(c.w);
      cfr[ks] = t;
    }
    int col = w * 16 + lr;
    f32x4 hacc = (f32x4){0.f, 0.f, 0.f, 0.f};
    #pragma unroll
    for (int ks = 0; ks < 4; ks++) {
      bf16x8 bfr = *(const bf16x8*)(WTf2o_p + col * NF + ks * 32 + lg * 8);
      hacc = __builtin_amdgcn_mfma_f32_16x16x32_bf16(cfr[ks], bfr, hacc, 0, 0, 0);
    }
    float bv = bf2o_p[col];
    #pragma unroll
    for (int r = 0; r < 4; r++)
      hLDS[(4 * lg + r) * 132 + col] = __float2bfloat16(sspf(hacc[r] + bv));
    __syncthreads();
    bf16x8 hfr[4];
    #pragma unroll
    for (int ks = 0; ks < 4; ks++)
      hfr[ks] = *(const bf16x8*)&hLDS[lr * 132 + ks * 32 + lg * 8];
    f32x4 vacc = (f32x4){0.f, 0.f, 0.f, 0.f};
    #pragma unroll
    for (int ks = 0; ks < 4; ks++) {
      bf16x8 bfr = *(const bf16x8*)(WTd_p + col * NF + ks * 32 + lg * 8);
      vacc = __builtin_amdgcn_mfma_f32_16x16x32_bf16(hfr[ks], bfr, vacc, 0, 0, 0);
    }
    float bdv = bd_p[col];
    #pragma unroll
    for (int r = 0; r < 4; r++) {
      int row = rbase + 4 * lg + r;
      float xv = xg[row * NF + col] + vacc[r] + bdv + Nb[row * NF + col];
      xout[row * NF + col] = xv;
      xLDS[(4 * lg + r) * 133 + col] = xv;
    }
    __syncthreads();
  } else {
    int rr = tid >> 5, c0 = (tid & 31) * 4;
    int row = rbase + rr;
    float4 a = *(const float4*)&emb[Z[row] * NF + c0];
    *(float4*)&xout[row * NF + c0] = a;
    xLDS[rr * 133 + c0 + 0] = a.x; xLDS[rr * 133 + c0 + 1] = a.y;
    xLDS[rr * 133 + c0 + 2] = a.z; xLDS[rr * 133 + c0 + 3] = a.w;
    __syncthreads();
  }

  // phase B: 8 waves = 4 projections x 2 col-halves
  int z = w & 3, half = w >> 2;
  const __hip_bfloat16* WT = WTl + ((z == 0) ? 0 : (z + 2)) * (NF * NF);
  float am = (z > 0) ? amask[rbase + lr] : 1.0f;
  bf16x8 afr[4];
  #pragma unroll
  for (int ks = 0; ks < 4; ks++) {
    int k0 = ks * 32 + lg * 8;
    bf16x8 t;
    #pragma unroll
    for (int jj = 0; jj < 8; jj++)
      t[jj] = (short)f2bf(xLDS[lr * 133 + k0 + jj] * am);
    afr[ks] = t;
  }

  f32x4 acc[4];
  #pragma unroll
  for (int t = 0; t < 4; t++) acc[t] = (f32x4){0.f, 0.f, 0.f, 0.f};
  #pragma unroll
  for (int ks = 0; ks < 4; ks++)
    #pragma unroll
    for (int t = 0; t < 4; t++) {
      int nt = half * 4 + t;
      bf16x8 bfr = *(const bf16x8*)(WT + (nt * 16 + lr) * NF + ks * 32 + lg * 8);
      acc[t] = __builtin_amdgcn_mfma_f32_16x16x32_bf16(afr[ks], bfr, acc[t], 0, 0, 0);
    }

  if (z < 3) {
    __hip_bfloat16* out = (z == 0) ? ybf : (z == 1) ? Qw : Kw;
    #pragma unroll
    for (int t = 0; t < 4; t++) {
      int col = (half * 4 + t) * 16 + lr;
      #pragma unroll
      for (int r = 0; r < 4; r++) {
        int orow = rbase + lg * 4 + r;
        float o = acc[t][r];
        if (z > 0) o = sspf(o);
        out[orow * NF + col] = __float2bfloat16(o);
      }
    }
  } else {
    int b = blockIdx.x >> 4;
    int ar0 = (blockIdx.x & 15) * 16 + lg * 4;
    #pragma unroll
    for (int t = 0; t < 4; t++) {
      int col = (half * 4 + t) * 16 + lr;
      #pragma unroll
      for (int r = 0; r < 4; r++)
        VwT[(b * NF + col) * NA + ar0 + r] = __float2bfloat16(sspf(acc[t][r]));
    }
  }
}

// ---------------- fa: blocks 0..255 attn-core, 256..4351 filter ----------------
__global__ __launch_bounds__(256) void k_fa(
    const __hip_bfloat16* __restrict__ ybf, const int* __restrict__ nbrs,
    const float* __restrict__ pos, const float* __restrict__ nmask,
    const __hip_bfloat16* __restrict__ Wfb_l, float* __restrict__ cOut,
    const __hip_bfloat16* __restrict__ Qw, const __hip_bfloat16* __restrict__ Kw,
    const __hip_bfloat16* __restrict__ VwT, const float* __restrict__ amask,
    float* __restrict__ Nb) {
  __shared__ char smem[8832];
  int tid = threadIdx.x;
  int lane = tid & 63, w = tid >> 6, lr = lane & 15, lg = lane >> 4;

  if (blockIdx.x >= 256) {
    // ================= filter =================
    // XCD swizzle: XCD r handles atoms [512r, 512r+512) = batches {2r, 2r+1}
    int bid = blockIdx.x - 256;
    int atom = ((bid & 7) << 9) + (bid >> 3);
    __hip_bfloat16* FF  = (__hip_bfloat16*)smem;            // [64][40]  5120 B
    float (*d3l)[4]     = (float(*)[4])(smem + 5120);       // [64][4]   1024 B
    int* jl             = (int*)(smem + 6144);              // [64]       256 B
    int brow = atom & ~(NA - 1);
    const unsigned short* yu = (const unsigned short*)ybf;

    {
      int n = tid & 63;
      int j = nbrs[atom * NNBH + n];
      float px = pos[(brow + j) * 3 + 0] - pos[atom * 3 + 0];
      float py = pos[(brow + j) * 3 + 1] - pos[atom * 3 + 1];
      float pz = pos[(brow + j) * 3 + 2] - pos[atom * 3 + 2];
      float m = nmask[atom * NNBH + n];
      float r = sqrtf(px * px + py * py + pz * pz + 1e-12f) * m;
      float inv = 1.0f / (r + 1e-9f);
      float fc = (r < 5.0f) ? (0.5f * cosf(0.62831853071795865f * r) + 0.5f) * m : 0.0f;
      float xe = expf(-r);
      float l1 = log2f(xe + 1e-10f);
      float l2 = log2f(1.0f - xe + 1e-10f);
      if (tid < NNBH) {
        jl[n] = (brow + j) * NF;
        d3l[n][0] = 0.f;
        d3l[n][1] = px * inv;
        d3l[n][2] = py * inv;
        d3l[n][3] = pz * inv;
      }
      int kq = tid >> 6;
      bf16x8 v;
      #pragma unroll
      for (int j8 = 0; j8 < 8; j8++) {
        int k = kq * 8 + j8;
        float val = 0.f;
        if (k < NK)
          val = BINOM_C[k] * exp2f((float)k * l1 + (float)(24 - k) * l2) * fc;
        v[j8] = (short)f2bf(val);
      }
      *(bf16x8*)&FF[n * 40 + kq * 8] = v;
    }
    __syncthreads();

    bf16x8 af[4];
    #pragma unroll
    for (int mt = 0; mt < 4; mt++)
      af[mt] = *(bf16x8*)&FF[(16 * mt + lr) * 40 + lg * 8];

    f32x4 as_[4][2], ap_[4][2];
    #pragma unroll
    for (int mt = 0; mt < 4; mt++)
      #pragma unroll
      for (int nt2 = 0; nt2 < 2; nt2++) {
        as_[mt][nt2] = (f32x4){0.f, 0.f, 0.f, 0.f};
        ap_[mt][nt2] = (f32x4){0.f, 0.f, 0.f, 0.f};
      }
    #pragma unroll
    for (int nt2 = 0; nt2 < 2; nt2++) {
      int col = 32 * w + 16 * nt2 + lr;
      bf16x8 bs = *(const bf16x8*)&Wfb_l[col * 32 + lg * 8];
      bf16x8 bp = *(const bf16x8*)&Wfb_l[(128 + col) * 32 + lg * 8];
      #pragma unroll
      for (int mt = 0; mt < 4; mt++) {
        as_[mt][nt2] = __builtin_amdgcn_mfma_f32_16x16x32_bf16(af[mt], bs, as_[mt][nt2], 0, 0, 0);
        ap_[mt][nt2] = __builtin_amdgcn_mfma_f32_16x16x32_bf16(af[mt], bp, ap_[mt][nt2], 0, 0, 0);
      }
    }

    // contraction: yj direct from global (coalesced u16, L2-local after swizzle)
    int rb[4][4];
    #pragma unroll
    for (int mt = 0; mt < 4; mt++)
      #pragma unroll
      for (int r = 0; r < 4; r++)
        rb[mt][r] = jl[16 * mt + 4 * lg + r];
    int f0 = 32 * w + lr, f1 = f0 + 16;

    float qs[2] = {0.f, 0.f}, q1[2] = {0.f, 0.f}, q2[2] = {0.f, 0.f}, q3[2] = {0.f, 0.f};
    #pragma unroll
    for (int mt = 0; mt < 4; mt++) {
      #pragma unroll
      for (int r = 0; r < 4; r++) {
        int n = 16 * mt + 4 * lg + r;
        float4 dv = *(const float4*)&d3l[n][0];
        unsigned short u0 = yu[rb[mt][r] + f0];
        unsigned short u1 = yu[rb[mt][r] + f1];
        float yv0 = __bfloat162float(*(__hip_bfloat16*)&u0);
        float yv1 = __bfloat162float(*(__hip_bfloat16*)&u1);
        qs[0] += yv0 * as_[mt][0][r];
        qs[1] += yv1 * as_[mt][1][r];
        float pw0 = yv0 * ap_[mt][0][r];
        float pw1 = yv1 * ap_[mt][1][r];
        q1[0] += dv.y * pw0;  q1[1] += dv.y * pw1;
        q2[0] += dv.z * pw0;  q2[1] += dv.z * pw1;
        q3[0] += dv.w * pw0;  q3[1] += dv.w * pw1;
      }
    }
    #pragma unroll
    for (int nt2 = 0; nt2 < 2; nt2++) {
      float a = qs[nt2], b1 = q1[nt2], b2 = q2[nt2], b3 = q3[nt2];
      a  += __shfl_xor(a, 16);  a  += __shfl_xor(a, 32);
      b1 += __shfl_xor(b1, 16); b1 += __shfl_xor(b1, 32);
      b2 += __shfl_xor(b2, 16); b2 += __shfl_xor(b2, 32);
      b3 += __shfl_xor(b3, 16); b3 += __shfl_xor(b3, 32);
      if (lg == 0)
        cOut[atom * NF + 32 * w + 16 * nt2 + lr] = a + b1 * b1 + b2 * b2 + b3 * b3;
    }
  } else {
    // ================= attn-core -> Nb (blocks 0..255, overlap filter) =======
    int bb = blockIdx.x;
    bb = ((bb & 7) << 5) + (bb >> 3);      // batch-pair -> XCD mapping
    __hip_bfloat16* Plds = (__hip_bfloat16*)smem;           // [16][260] 8320 B
    float* mwl = (float*)(smem + 8320);                     // [4][16]
    float* swl = (float*)(smem + 8576);                     // [4][16]
    int b = bb >> 4, qt = bb & 15;
    int qbase = b * NA + qt * 16;
    const float scale = 0.08838834764831845f;

    bf16x8 qf[4];
    #pragma unroll
    for (int ks = 0; ks < 4; ks++)
      qf[ks] = *(const bf16x8*)&Qw[(qbase + lr) * NF + ks * 32 + lg * 8];

    f32x4 sacc[4];
    #pragma unroll
    for (int ntc = 0; ntc < 4; ntc++) sacc[ntc] = (f32x4){0.f, 0.f, 0.f, 0.f};
    #pragma unroll
    for (int ks = 0; ks < 4; ks++)
      #pragma unroll
      for (int ntc = 0; ntc < 4; ntc++) {
        bf16x8 kf = *(const bf16x8*)&Kw[(b * NA + w * 64 + ntc * 16 + lr) * NF + ks * 32 + lg * 8];
        sacc[ntc] = __builtin_amdgcn_mfma_f32_16x16x32_bf16(qf[ks], kf, sacc[ntc], 0, 0, 0);
      }

    float kam[4];
    #pragma unroll
    for (int ntc = 0; ntc < 4; ntc++)
      kam[ntc] = (1.0f - amask[b * NA + w * 64 + ntc * 16 + lr]) * (-1e9f);

    #pragma unroll
    for (int r = 0; r < 4; r++) {
      float lv[4], cm = -1e30f;
      #pragma unroll
      for (int ntc = 0; ntc < 4; ntc++) {
        lv[ntc] = sacc[ntc][r] * scale + kam[ntc];
        cm = fmaxf(cm, lv[ntc]);
      }
      cm = fmaxf(cm, __shfl_xor(cm, 1)); cm = fmaxf(cm, __shfl_xor(cm, 2));
      cm = fmaxf(cm, __shfl_xor(cm, 4)); cm = fmaxf(cm, __shfl_xor(cm, 8));
      float ps = 0.f;
      #pragma unroll
      for (int ntc = 0; ntc < 4; ntc++) {
        float pp = expf(lv[ntc] - cm);
        Plds[(4 * lg + r) * 260 + w * 64 + ntc * 16 + lr] = __float2bfloat16(pp);
        ps += pp;
      }
      ps += __shfl_xor(ps, 1); ps += __shfl_xor(ps, 2);
      ps += __shfl_xor(ps, 4); ps += __shfl_xor(ps, 8);
      if (lr == 0) {
        mwl[w * 16 + 4 * lg + r] = cm;
        swl[w * 16 + 4 * lg + r] = ps;
      }
    }
    __syncthreads();

    float ec[4][4], inv_[4];
    #pragma unroll
    for (int r = 0; r < 4; r++) {
      int row = 4 * lg + r;
      float m0 = mwl[row], m1 = mwl[16 + row], m2 = mwl[32 + row], m3 = mwl[48 + row];
      float M = fmaxf(fmaxf(m0, m1), fmaxf(m2, m3));
      float e0 = expf(m0 - M), e1 = expf(m1 - M), e2 = expf(m2 - M), e3 = expf(m3 - M);
      ec[0][r] = e0; ec[1][r] = e1; ec[2][r] = e2; ec[3][r] = e3;
      float s = swl[row] * e0 + swl[16 + row] * e1 + swl[32 + row] * e2 + swl[48 + row] * e3;
      inv_[r] = amask[qbase + row] / s;
    }

    f32x4 O[2];
    O[0] = (f32x4){0.f, 0.f, 0.f, 0.f};
    O[1] = (f32x4){0.f, 0.f, 0.f, 0.f};
    #pragma unroll
    for (int c = 0; c < 4; c++) {
      bf16x8 pf[2];
      #pragma unroll
      for (int s2 = 0; s2 < 2; s2++)
        pf[s2] = *(const bf16x8*)&Plds[lr * 260 + c * 64 + s2 * 32 + lg * 8];
      f32x4 tc[2];
      tc[0] = (f32x4){0.f, 0.f, 0.f, 0.f};
      tc[1] = (f32x4){0.f, 0.f, 0.f, 0.f};
      #pragma unroll
      for (int s2 = 0; s2 < 2; s2++)
        #pragma unroll
        for (int j = 0; j < 2; j++) {
          bf16x8 vf = *(const bf16x8*)&VwT[(b * NF + (2 * w + j) * 16 + lr) * NA + c * 64 + s2 * 32 + lg * 8];
          tc[j] = __builtin_amdgcn_mfma_f32_16x16x32_bf16(pf[s2], vf, tc[j], 0, 0, 0);
        }
      #pragma unroll
      for (int j = 0; j < 2; j++)
        #pragma unroll
        for (int r = 0; r < 4; r++)
          O[j][r] += ec[c][r] * tc[j][r];
    }

    #pragma unroll
    for (int r = 0; r < 4; r++) {
      int q = qbase + 4 * lg + r;
      #pragma unroll
      for (int j = 0; j < 2; j++) {
        int col = (2 * w + j) * 16 + lr;
        Nb[q * NF + col] = O[j][r] * inv_[r];
      }
    }
  }
}

// ---------------- final: hv(L2) + residual -> x (512 thr) ----------------
__global__ __launch_bounds__(512) void k_final(
    const float* __restrict__ Cb, const float* __restrict__ Nb,
    const __hip_bfloat16* __restrict__ WTf2o_p, const float* __restrict__ bf2o_p,
    const __hip_bfloat16* __restrict__ WTd_p, const float* __restrict__ bd_p,
    float* __restrict__ x) {
  __shared__ __hip_bfloat16 hLDS[16 * 132];
  int tid = threadIdx.x;
  int w = tid >> 6, ln = tid & 63, lr = ln & 15, lg = ln >> 4;
  int rbase = blockIdx.x * 16;
  int col = w * 16 + lr;

  bf16x8 cfr[4];
  const float* cr = Cb + (rbase + lr) * NF;
  #pragma unroll
  for (int ks = 0; ks < 4; ks++) {
    int k0 = ks * 32 + lg * 8;
    float4 a = *(const float4*)&cr[k0];
    float4 c = *(const float4*)&cr[k0 + 4];
    bf16x8 t;
    t[0] = (short)f2bf(a.x); t[1] = (short)f2bf(a.y);
    t[2] = (short)f2bf(a.z); t[3] = (short)f2bf(a.w);
    t[4] = (short)f2bf(c.x); t[5] = (short)f2bf(c.y);
    t[6] = (short)f2bf(c.z); t[7] = (short)f2bf(c.w);
    cfr[ks] = t;
  }
  f32x4 hacc = (f32x4){0.f, 0.f, 0.f, 0.f};
  #pragma unroll
  for (int ks = 0; ks < 4; ks++) {
    bf16x8 bfr = *(const bf16x8*)(WTf2o_p + col * NF + ks * 32 + lg * 8);
    hacc = __builtin_amdgcn_mfma_f32_16x16x32_bf16(cfr[ks], bfr, hacc, 0, 0, 0);
  }
  float bv = bf2o_p[col];
  #pragma unroll
  for (int r = 0; r < 4; r++)
    hLDS[(4 * lg + r) * 132 + col] = __float2bfloat16(sspf(hacc[r] + bv));
  __syncthreads();
  bf16x8 hfr[4];
  #pragma unroll
  for (int ks = 0; ks < 4; ks++)
    hfr[ks] = *(const bf16x8*)&hLDS[lr * 132 + ks * 32 + lg * 8];
  f32x4 vacc = (f32x4){0.f, 0.f, 0.f, 0.f};
  #pragma unroll
  for (int ks = 0; ks < 4; ks++) {
    bf16x8 bfr = *(const bf16x8*)(WTd_p + col * NF + ks * 32 + lg * 8);
    vacc = __builtin_amdgcn_mfma_f32_16x16x32_bf16(hfr[ks], bfr, vacc, 0, 0, 0);
  }
  float bdv = bd_p[col];
  #pragma unroll
  for (int r = 0; r < 4; r++) {
    int row = rbase + 4 * lg + r;
    x[row * NF + col] += vacc[r] + bdv + Nb[row * NF + col];
  }
}

// ---------------- host launch ----------------
extern "C" void kernel_launch(void* const* d_in, const int* in_sizes, int n_in,
                              void* d_out, int out_size, void* d_ws, size_t ws_size,
                              hipStream_t stream) {
  const float* pos   = (const float*)d_in[0];
  const float* nmask = (const float*)d_in[1];
  const float* amask = (const float*)d_in[2];
  const float* emb   = (const float*)d_in[3];
  const float* Wfs   = (const float*)d_in[4];
  const float* Wfp   = (const float*)d_in[5];
  const float* Win   = (const float*)d_in[6];
  const float* Wf2o  = (const float*)d_in[7];
  const float* bf2o  = (const float*)d_in[8];
  const float* Wd    = (const float*)d_in[9];
  const float* bd    = (const float*)d_in[10];
  const float* Wq    = (const float*)d_in[11];
  const float* Wk    = (const float*)d_in[12];
  const float* Wv    = (const float*)d_in[13];
  const int*   Z     = (const int*)d_in[14];
  const int*   nbrs  = (const int*)d_in[15];

  float* x = (float*)d_out;
  float* wsf = (float*)d_ws;
  const int S = NATOM * NF;                               // 524288
  float* Cb = wsf;                                        // S f32
  float* Nb = wsf + S;                                    // S f32
  __hip_bfloat16* ybf = (__hip_bfloat16*)(wsf + 2 * S);
  __hip_bfloat16* Qw  = ybf + S;
  __hip_bfloat16* Kw  = Qw + S;
  __hip_bfloat16* VwT = Kw + S;                           // [b][f][row]
  __hip_bfloat16* WT  = VwT + S;                          // 18*16384 bf16
  __hip_bfloat16* Wfb = WT + 18 * 16384;                  // 24576 bf16

  k_init<<<dim3(1248), dim3(256), 0, stream>>>(
      Win, Wf2o, Wd, Wq, Wk, Wv, Wfs, Wfp, WT, Wfb);

  for (int l = 0; l < 3; l++) {
    const __hip_bfloat16* WTl = WT + l * 6 * 16384;
    if (l == 0)
      k_proj<0><<<dim3(256), dim3(512), 0, stream>>>(
          nullptr, Z, emb, nullptr, nullptr, nullptr, nullptr, nullptr, nullptr,
          amask, WTl, x, ybf, Qw, Kw, VwT);
    else {
      const __hip_bfloat16* WTp = WT + (l - 1) * 6 * 16384;
      k_proj<1><<<dim3(256), dim3(512), 0, stream>>>(
          x, nullptr, nullptr, Cb, Nb, WTp + 16384, bf2o + (l - 1) * NF,
          WTp + 2 * 16384, bd + (l - 1) * NF, amask, WTl, x, ybf, Qw, Kw, VwT);
    }
    k_fa<<<dim3(4096 + 256), dim3(256), 0, stream>>>(
        ybf, nbrs, pos, nmask, Wfb + l * 8192, Cb, Qw, Kw, VwT, amask, Nb);
  }
  const __hip_bfloat16* WT2 = WT + 2 * 6 * 16384;
  k_final<<<dim3(256), dim3(512), 0, stream>>>(
      Cb, Nb, WT2 + 16384, bf2o + 2 * NF, WT2 + 2 * 16384, bd + 2 * NF, x);
}